// Round 10
// baseline (1082.770 us; speedup 1.0000x reference)
//
#include <hip/hip_runtime.h>
#include <hip/hip_bf16.h>

// UCCAEncoder: 3x EdgeConv(max) + FFN + gather. R19:
//  - edge kernel: B (W2^T, 0.5MB L2-resident, zero cross-use reuse in LDS)
//    now loads DIRECT global->register fragments (4 x dwordx4 per half-step
//    per wave), eliminating the B DMA + B ds_reads. Cycle model (corrected
//    21cy/MFMA): LDS port was 66% busy (highest resource) -> ~26% now.
//    Consequences: no DMA at all -> no manual vmcnt (compiler tracks register
//    loads exactly); barriers 32 -> 17 (raw s_barrier + lgkmcnt(0), guarding
//    only the 8KB As); B(h+1) issue before h's 16-MFMA cluster hides L2 lat.
//    LDS = As 8KB + 16KB epilogue key tile + sdst/ssrc = 24.6KB, (256,3).
//  - keeps R18: merged+pipelined node GEMM, batched prep, ffn retile+fused
//    gather, decode x2, LDS key-tile epilogue, sorted edges, XCD swizzle.

#define N_NODES 16384
#define EDGES   262144
#define HDIM    512
#define SEQ     2048

typedef __attribute__((ext_vector_type(8))) short short8;
typedef __attribute__((ext_vector_type(8))) _Float16 half8;
typedef __attribute__((ext_vector_type(2))) _Float16 half2v;
typedef __attribute__((ext_vector_type(4))) float f32x4;

__device__ __forceinline__ void gld16(const void* g, void* l) {
    __builtin_amdgcn_global_load_lds(
        (const __attribute__((address_space(1))) void*)g,
        (__attribute__((address_space(3))) void*)l, 16, 0, 0);
}
__device__ __forceinline__ unsigned short f2b(float f) {   // fp32 -> bf16 RNE
    unsigned int x = __float_as_uint(f);
    return (unsigned short)((x + 0x7fffu + ((x >> 16) & 1u)) >> 16);
}
__device__ __forceinline__ unsigned short f2h(float f) {   // fp32 -> fp16 bits
    _Float16 h = (_Float16)f;
    return __builtin_bit_cast(unsigned short, h);
}
// packed fp16: z = max(u+v, 0) (v_pk_add_f16 + v_pk_max_f16)
__device__ __forceinline__ unsigned int zpack_h(unsigned int u, unsigned int v) {
    half2v a = __builtin_bit_cast(half2v, u);
    half2v b = __builtin_bit_cast(half2v, v);
    half2v s = a + b;
    half2v z = {(_Float16)0.f, (_Float16)0.f};
    half2v r = __builtin_elementwise_max(s, z);
    return __builtin_bit_cast(unsigned int, r);
}
// ---- Bk=32 LDS swizzle (node/FFN GEMMs): slot = seg ^ ((row>>1)&3), row stride 64B
__device__ __forceinline__ short8 frag_ld(const short* S, int row, int q) {
    int p = q ^ ((row >> 1) & 3);
    return *(const short8*)(S + row * 32 + p * 8);
}
__device__ __forceinline__ void stage_tile(const short* G, int kc, short* S, int t) {
#pragma unroll
    for (int it = 0; it < 2; ++it) {
        int lin = it * 256 + t;
        int row = lin >> 2, p = lin & 3;
        int q = p ^ ((row >> 1) & 3);
        gld16(G + (size_t)row * HDIM + kc + q * 8, S + lin * 8);
    }
}
// ---- Bk=64 LDS swizzle (edge A tile): row stride 128B = bank wrap ->
//      slot = seg ^ ((row>>1)&7) ^ (row&1); 8 segs of 8 els per row.
__device__ __forceinline__ half8 frag64(const short* S, int row, int q) {
    int p = q ^ ((row >> 1) & 7) ^ (row & 1);
    return *(const half8*)(S + row * 64 + p * 8);
}

// ================= edge sort (counting sort by dst) =================
__global__ __launch_bounds__(256) void hist_kernel(
    const int* __restrict__ dst, int* __restrict__ hist) {
    int idx = blockIdx.x * 256 + threadIdx.x;
    atomicAdd(&hist[dst[idx]], 1);
}
__global__ __launch_bounds__(256) void scan_kernel(
    const int* __restrict__ hist, int* __restrict__ cursor) {
    __shared__ int part[256];
    const int t = threadIdx.x, base = t * 64;
    int sum = 0;
    for (int i = 0; i < 64; ++i) sum += hist[base + i];
    part[t] = sum;
    __syncthreads();
    int run = 0;
    for (int i = 0; i < t; ++i) run += part[i];
    for (int i = 0; i < 64; ++i) {
        int h = hist[base + i];
        cursor[base + i] = run;
        run += h;
    }
}
__global__ __launch_bounds__(256) void scatter_kernel(
    const int* __restrict__ dst, const int* __restrict__ src,
    int* __restrict__ cursor, int* __restrict__ dstS, int* __restrict__ srcS) {
    int idx = blockIdx.x * 256 + threadIdx.x;
    int d = dst[idx];
    int p = atomicAdd(&cursor[d], 1);
    dstS[p] = d;
    srcS[p] = src[idx];
}

// ================= weights / input prep =================
// ALL conv layers batched: grid z = 9 (layer = z/3, which = z%3).
__global__ __launch_bounds__(256) void prep_weights_all_kernel(
    const float* __restrict__ w1_0, const float* __restrict__ w2_0,
    const float* __restrict__ w1_1, const float* __restrict__ w2_1,
    const float* __restrict__ w1_2, const float* __restrict__ w2_2,
    short* __restrict__ outbase) {
    __shared__ float tile[32][33];
    const int z = blockIdx.z;
    const int layer = z / 3, which = z % 3;
    const float* w1 = layer == 0 ? w1_0 : (layer == 1 ? w1_1 : w1_2);
    const float* w2 = layer == 0 ? w2_0 : (layer == 1 ? w2_1 : w2_2);
    const int k0 = blockIdx.x * 32, n0 = blockIdx.y * 32;
    const int tx = threadIdx.x, ty = threadIdx.y;
#pragma unroll
    for (int i = 0; i < 4; ++i) {
        int k = k0 + ty + i * 8, n = n0 + tx;
        float v;
        if (which == 0)      v = w1[k * 512 + n] - w1[(k + 512) * 512 + n];
        else if (which == 1) v = w1[(k + 512) * 512 + n];
        else                 v = w2[k * 512 + n];
        tile[ty + i * 8][tx] = v;
    }
    __syncthreads();
    short* out = outbase + (size_t)(layer * 3 + which) * 512 * 512;
#pragma unroll
    for (int i = 0; i < 4; ++i) {
        int n = n0 + ty + i * 8, k = k0 + tx;
        float v = tile[tx][ty + i * 8];
        out[(size_t)n * 512 + k] = (short)(which == 2 ? f2h(v) : f2b(v));
    }
}
// FFN mats (bf16): z=0 fw1, z=1 fw2
__global__ __launch_bounds__(256) void tr_kernel(
    const float* __restrict__ W1, const float* __restrict__ W2,
    short* __restrict__ T1, short* __restrict__ T2) {
    __shared__ float tile[32][33];
    const float* W = blockIdx.z ? W2 : W1;
    short* T = blockIdx.z ? T2 : T1;
    const int k0 = blockIdx.x * 32, n0 = blockIdx.y * 32;
    const int tx = threadIdx.x, ty = threadIdx.y;
#pragma unroll
    for (int i = 0; i < 4; ++i)
        tile[ty + i * 8][tx] = W[(k0 + ty + i * 8) * 512 + n0 + tx];
    __syncthreads();
#pragma unroll
    for (int i = 0; i < 4; ++i)
        T[(size_t)(n0 + ty + i * 8) * 512 + k0 + tx] = (short)f2b(tile[tx][ty + i * 8]);
}
__global__ __launch_bounds__(256) void cvt_bf16_kernel(
    const float* __restrict__ x, short* __restrict__ xb) {
    int idx = blockIdx.x * 256 + threadIdx.x;
    float4 v = ((const float4*)x)[idx];
    uint2 o;
    o.x = (unsigned int)f2b(v.x) | ((unsigned int)f2b(v.y) << 16);
    o.y = (unsigned int)f2b(v.z) | ((unsigned int)f2b(v.w) << 16);
    ((uint2*)xb)[idx] = o;
}

// ========== fused U/V node GEMM, merged + counted-vmcnt dbuf pipeline ==========
__global__ __launch_bounds__(256, 2) void node_gemm_uv_kernel(
    const short* __restrict__ A, const short* __restrict__ WdT,
    const short* __restrict__ w1bT, const float* __restrict__ b1,
    short* __restrict__ U, short* __restrict__ V) {
    __shared__ short As[2][128 * 32];
    __shared__ short Bu[2][128 * 32];
    __shared__ short Bv[2][128 * 32];   // 48 KB total
    const int t = threadIdx.x;
    const int m0 = blockIdx.x * 128, n0 = blockIdx.y * 128;
    const int w = t >> 6, l = t & 63;
    const int wm = (w & 1) * 64, wn = (w >> 1) * 64;
    const short* Ag = A + (size_t)m0 * HDIM;
    const short* Ug = WdT + (size_t)n0 * HDIM;
    const short* Vg = w1bT + (size_t)n0 * HDIM;
    f32x4 aU[4][4] = {}, aV[4][4] = {};
    stage_tile(Ag, 0, As[0], t);
    stage_tile(Ug, 0, Bu[0], t);
    stage_tile(Vg, 0, Bv[0], t);
#pragma unroll
    for (int hh = 0; hh < 16; ++hh) {
        if (hh < 15) {
            const int kc1 = (hh + 1) * 32;
            stage_tile(Ag, kc1, As[(hh + 1) & 1], t);
            stage_tile(Ug, kc1, Bu[(hh + 1) & 1], t);
            stage_tile(Vg, kc1, Bv[(hh + 1) & 1], t);
            asm volatile("s_waitcnt vmcnt(6)" ::: "memory");
        } else {
            asm volatile("s_waitcnt vmcnt(0)" ::: "memory");
        }
        __builtin_amdgcn_s_barrier();
        asm volatile("" ::: "memory");
        const short* Ab = As[hh & 1];
        const short* Bub = Bu[hh & 1];
        const short* Bvb = Bv[hh & 1];
        short8 a[4], bu[4], bv[4];
#pragma unroll
        for (int mt = 0; mt < 4; ++mt) a[mt] = frag_ld(Ab, wm + mt * 16 + (l & 15), l >> 4);
#pragma unroll
        for (int nt = 0; nt < 4; ++nt) {
            bu[nt] = frag_ld(Bub, wn + nt * 16 + (l & 15), l >> 4);
            bv[nt] = frag_ld(Bvb, wn + nt * 16 + (l & 15), l >> 4);
        }
#pragma unroll
        for (int mt = 0; mt < 4; ++mt)
#pragma unroll
            for (int nt = 0; nt < 4; ++nt) {
                aU[mt][nt] = __builtin_amdgcn_mfma_f32_16x16x32_bf16(a[mt], bu[nt], aU[mt][nt], 0, 0, 0);
                aV[mt][nt] = __builtin_amdgcn_mfma_f32_16x16x32_bf16(a[mt], bv[nt], aV[mt][nt], 0, 0, 0);
            }
        asm volatile("" ::: "memory");
        __builtin_amdgcn_s_barrier();
    }
#pragma unroll
    for (int mt = 0; mt < 4; ++mt) {
        int m = m0 + wm + mt * 16 + (l >> 4) * 4;
#pragma unroll
        for (int nt = 0; nt < 4; ++nt) {
            int n = n0 + wn + nt * 16 + (l & 15);
            float bv = b1[n];
#pragma unroll
            for (int r = 0; r < 4; ++r) {
                U[(size_t)(m + r) * HDIM + n] = (short)f2h(aU[mt][nt][r] + bv);
                V[(size_t)(m + r) * HDIM + n] = (short)f2h(aV[mt][nt][r]);
            }
        }
    }
}

// ====== edge GEMM: B direct L2->reg, A in LDS, 64e x 256n, 17 barriers ======
__device__ __forceinline__ unsigned int fkey(float m) {    // monotone fp32->uint
    unsigned int b = __float_as_uint(m);
    return ((int)b < 0) ? ~b : (b | 0x80000000u);
}
__device__ __forceinline__ void kflush(unsigned int* K, int d, int col, float m) {
    atomicMax(K + (((size_t)d) << 9) + col, fkey(m));
}
__global__ __launch_bounds__(256, 3) void edge_mfma_kernel(
    const short* __restrict__ U, const short* __restrict__ V,
    const short* __restrict__ Wt, const int* __restrict__ srcS,
    const int* __restrict__ dstS, unsigned int* __restrict__ K) {
    __shared__ short As[64 * 64];            // 8 KB (z, fp16, Bk=64, single buf)
    __shared__ unsigned int ktile[16 * 256]; // 16 KB (epilogue key tile)
    __shared__ int sdst[64], ssrc[64];
    const int t = threadIdx.x;
    // XCD swizzle: L%8 = XCD; the 2 n-halves of edge-group g are 8 apart (same XCD).
    const int L  = blockIdx.x;                 // 0..8191
    const int g  = (L >> 4) * 8 + (L & 7);     // edge-group 0..4095 (64 edges each)
    const int nh = (L >> 3) & 1;               // n-half
    const int e0 = g * 64, n0 = nh * 256;
    if (t < 64) { sdst[t] = dstS[e0 + t]; ssrc[t] = srcS[e0 + t]; }
    __syncthreads();
    const int w = t >> 6, l = t & 63;
    const int wnb = w * 64;                    // 64-col slice
    const int lm = l & 15;
    const int arow = t >> 2, s0 = (t & 3) * 2; // thread covers 32B (segs s0,s0+1)
    const int perm = ((arow >> 1) & 7) ^ (arow & 1);
    const int p0 = s0 ^ perm, p1 = (s0 + 1) ^ perm;
    const short* up = U + (((size_t)sdst[arow]) << 9) + s0 * 8;
    const short* vp = V + (((size_t)ssrc[arow]) << 9) + s0 * 8;
    // per-thread B-fragment base: row = n0 + wnb + lm, col-seg = (l>>4)*8
    const short* bp = Wt + (size_t)(n0 + wnb + lm) * HDIM + (l >> 4) * 8;
    unsigned int* As_u = (unsigned int*)As;
    f32x4 acc[4][4] = {};
    half8 bc[4], bn[4];
    uint4 pu0, pu1, pv0, pv1;
    // ---- prologue: B(0), A(0), zpack->As(0), A(1), barrier ----
#pragma unroll
    for (int nt = 0; nt < 4; ++nt) bc[nt] = *(const half8*)(bp + nt * 16 * HDIM);
    pu0 = *(const uint4*)(up);      pu1 = *(const uint4*)(up + 8);
    pv0 = *(const uint4*)(vp);      pv1 = *(const uint4*)(vp + 8);
    {
        uint4 z0, z1;
        z0.x = zpack_h(pu0.x, pv0.x); z0.y = zpack_h(pu0.y, pv0.y);
        z0.z = zpack_h(pu0.z, pv0.z); z0.w = zpack_h(pu0.w, pv0.w);
        z1.x = zpack_h(pu1.x, pv1.x); z1.y = zpack_h(pu1.y, pv1.y);
        z1.z = zpack_h(pu1.z, pv1.z); z1.w = zpack_h(pu1.w, pv1.w);
        *(uint4*)(As_u + arow * 32 + p0 * 4) = z0;
        *(uint4*)(As_u + arow * 32 + p1 * 4) = z1;
    }
    pu0 = *(const uint4*)(up + 64); pu1 = *(const uint4*)(up + 72);
    pv0 = *(const uint4*)(vp + 64); pv1 = *(const uint4*)(vp + 72);
    asm volatile("s_waitcnt lgkmcnt(0)" ::: "memory");
    __builtin_amdgcn_s_barrier();
    asm volatile("" ::: "memory");
    // ---- 8 K-steps; step j: half-steps h0=2j (B=bc), h1=2j+1 (B=bn).
    // B(h+1) issued before h's 16-MFMA cluster (~330cy) -> L2 latency hidden.
    // Compiler inserts exact counted vmcnt for bc/bn/pu/pv (plain reg loads);
    // raw barriers (lgkmcnt-only) guard the single-buffered As.
#pragma unroll
    for (int j = 0; j < 8; ++j) {
        const int h1 = 2 * j + 1;
        // issue B(h1)
#pragma unroll
        for (int nt = 0; nt < 4; ++nt)
            bn[nt] = *(const half8*)(bp + nt * 16 * HDIM + h1 * 32);
        // even half-step: A segs q = l>>4
        __builtin_amdgcn_s_setprio(1);
#pragma unroll
        for (int mt = 0; mt < 4; ++mt) {
            half8 a = frag64(As, mt * 16 + lm, (l >> 4));
#pragma unroll
            for (int nt = 0; nt < 4; ++nt)
                acc[mt][nt] = __builtin_amdgcn_mfma_f32_16x16x32_f16(a, bc[nt], acc[mt][nt], 0, 0, 0);
        }
        __builtin_amdgcn_s_setprio(0);
        // issue B(2j+2) for next iteration
        if (j < 7) {
#pragma unroll
            for (int nt = 0; nt < 4; ++nt)
                bc[nt] = *(const half8*)(bp + nt * 16 * HDIM + (h1 + 1) * 32);
        }
        // odd half-step: A segs q = 4 + (l>>4)
        __builtin_amdgcn_s_setprio(1);
#pragma unroll
        for (int mt = 0; mt < 4; ++mt) {
            half8 a = frag64(As, mt * 16 + lm, 4 + (l >> 4));
#pragma unroll
            for (int nt = 0; nt < 4; ++nt)
                acc[mt][nt] = __builtin_amdgcn_mfma_f32_16x16x32_f16(a, bn[nt], acc[mt][nt], 0, 0, 0);
        }
        __builtin_amdgcn_s_setprio(0);
        asm volatile("s_waitcnt lgkmcnt(0)" ::: "memory");
        __builtin_amdgcn_s_barrier();           // WAR: all waves done reading As(j)
        asm volatile("" ::: "memory");
        if (j < 7) {
            // zpack A(j+1) -> As(j+1); reload pu/pv <- A(j+2)
            uint4 z0, z1;
            z0.x = zpack_h(pu0.x, pv0.x); z0.y = zpack_h(pu0.y, pv0.y);
            z0.z = zpack_h(pu0.z, pv0.z); z0.w = zpack_h(pu0.w, pv0.w);
            z1.x = zpack_h(pu1.x, pv1.x); z1.y = zpack_h(pu1.y, pv1.y);
            z1.z = zpack_h(pu1.z, pv1.z); z1.w = zpack_h(pu1.w, pv1.w);
            *(uint4*)(As_u + arow * 32 + p0 * 4) = z0;
            *(uint4*)(As_u + arow * 32 + p1 * 4) = z1;
            if (j < 6) {
                const int kn = (j + 2) * 64;
                pu0 = *(const uint4*)(up + kn);      pu1 = *(const uint4*)(up + kn + 8);
                pv0 = *(const uint4*)(vp + kn);      pv1 = *(const uint4*)(vp + kn + 8);
            }
            asm volatile("s_waitcnt lgkmcnt(0)" ::: "memory");
            __builtin_amdgcn_s_barrier();       // RAW: As(j+1) visible to all
            asm volatile("" ::: "memory");
        }
    }
    // ===== epilogue: segment-max pre-reduced in LDS key tile, sparse flush =====
    const int dbase = sdst[0];
    const int drange = sdst[63] - dbase + 1;
    if (drange <= 16) {
#pragma unroll
        for (int i = 0; i < 16; ++i) ktile[i * 256 + t] = 0u;   // zero tile
        __syncthreads();
#pragma unroll
        for (int mt = 0; mt < 4; ++mt) {
            int base = mt * 16 + (l >> 4) * 4;
            int d0 = sdst[base], d1 = sdst[base + 1], d2 = sdst[base + 2], d3 = sdst[base + 3];
            int r0 = d0 - dbase, r1 = d1 - dbase, r2 = d2 - dbase, r3 = d3 - dbase;
#pragma unroll
            for (int nt = 0; nt < 4; ++nt) {
                int colb = wnb + nt * 16 + lm;
                f32x4 a = acc[mt][nt];
                float m = a[0];
                if (d1 == d0) m = fmaxf(m, a[1]);
                else { atomicMax(ktile + r0 * 256 + colb, fkey(m)); m = a[1]; }
                if (d2 == d1) m = fmaxf(m, a[2]);
                else { atomicMax(ktile + r1 * 256 + colb, fkey(m)); m = a[2]; }
                if (d3 == d2) m = fmaxf(m, a[3]);
                else { atomicMax(ktile + r2 * 256 + colb, fkey(m)); m = a[3]; }
                atomicMax(ktile + r3 * 256 + colb, fkey(m));
            }
        }
        __syncthreads();
        // flush non-empty rows: thread t owns column n0+t across all rows
#pragma unroll 4
        for (int r = 0; r < 16; ++r) {
            if (r < drange) {
                unsigned int kv = ktile[r * 256 + t];
                if (kv) atomicMax(K + (((size_t)(dbase + r)) << 9) + n0 + t, kv);
            }
        }
    } else {
        // fallback (degenerate range): direct run-compressed global flushes
#pragma unroll
        for (int mt = 0; mt < 4; ++mt) {
            int base = mt * 16 + (l >> 4) * 4;
            int d0 = sdst[base], d1 = sdst[base + 1], d2 = sdst[base + 2], d3 = sdst[base + 3];
#pragma unroll
            for (int nt = 0; nt < 4; ++nt) {
                int col = n0 + wnb + nt * 16 + lm;
                f32x4 a = acc[mt][nt];
                float m = a[0];
                if (d1 == d0) m = fmaxf(m, a[1]); else { kflush(K, d0, col, m); m = a[1]; }
                if (d2 == d1) m = fmaxf(m, a[2]); else { kflush(K, d1, col, m); m = a[2]; }
                if (d3 == d2) m = fmaxf(m, a[3]); else { kflush(K, d2, col, m); m = a[3]; }
                kflush(K, d3, col, m);
            }
        }
    }
}

// ======= decode keys -> h bf16 (x2 vectorized); re-zero keys for next layer =======
__global__ __launch_bounds__(256) void decode_kernel(
    unsigned int* __restrict__ K, const float* __restrict__ b2,
    short* __restrict__ hb) {
    int idx = blockIdx.x * 256 + threadIdx.x;          // 2 keys per thread
    uint2 k = ((uint2*)K)[idx];
    uint2 zz = {0u, 0u};
    ((uint2*)K)[idx] = zz;                             // init for next layer
    int c = (idx << 1) & (HDIM - 1);
    float v0 = 0.f, v1 = 0.f;
    if (k.x != 0u) {
        unsigned int b = (k.x & 0x80000000u) ? (k.x ^ 0x80000000u) : ~k.x;
        v0 = __uint_as_float(b) + b2[c];
    }
    if (k.y != 0u) {
        unsigned int b = (k.y & 0x80000000u) ? (k.y ^ 0x80000000u) : ~k.y;
        v1 = __uint_as_float(b) + b2[c + 1];
    }
    unsigned int o = (unsigned int)f2b(fmaxf(v0, 0.f))
                   | ((unsigned int)f2b(fmaxf(v1, 0.f)) << 16);
    ((unsigned int*)hb)[idx] = o;
}

// ========= MFMA GEMM (FFN), 64x128 tiles, optional sel-gather on A =========
__global__ __launch_bounds__(256) void ffn_gemm_kernel(
    const short* __restrict__ A, const int* __restrict__ sel,
    const short* __restrict__ Wt, const float* __restrict__ bias,
    short* __restrict__ Cb, float* __restrict__ Cf, int relu) {
    __shared__ short As[64 * 32];      // 4 KB
    __shared__ short Bs[128 * 32];     // 8 KB
    const int t = threadIdx.x;
    const int m0 = blockIdx.x * 64, n0 = blockIdx.y * 128;
    const int w = t >> 6, l = t & 63;
    const int wm = (w & 1) * 32, wn = (w >> 1) * 64;
    const int srow = t >> 2, sp = t & 3;
    const int sq = sp ^ ((srow >> 1) & 3);
    const short* ap;
    if (sel) {                                   // fused gather: row -> hb row
        int gr = m0 + srow;                      // 0..4095
        ap = A + (((size_t)((gr >> 9) * SEQ + sel[gr])) << 9);
    } else {
        ap = A + (size_t)(m0 + srow) * HDIM;
    }
    f32x4 acc[2][4] = {};
    for (int kc = 0; kc < HDIM; kc += 32) {
        gld16(ap + kc + sq * 8, As + t * 8);
        stage_tile(Wt + (size_t)n0 * HDIM, kc, Bs, t);
        __syncthreads();
        short8 a[2], b[4];
#pragma unroll
        for (int mt = 0; mt < 2; ++mt) a[mt] = frag_ld(As, wm + mt * 16 + (l & 15), l >> 4);
#pragma unroll
        for (int nt = 0; nt < 4; ++nt) b[nt] = frag_ld(Bs, wn + nt * 16 + (l & 15), l >> 4);
#pragma unroll
        for (int mt = 0; mt < 2; ++mt)
#pragma unroll
            for (int nt = 0; nt < 4; ++nt)
                acc[mt][nt] = __builtin_amdgcn_mfma_f32_16x16x32_bf16(a[mt], b[nt], acc[mt][nt], 0, 0, 0);
        __syncthreads();
    }
#pragma unroll
    for (int mt = 0; mt < 2; ++mt) {
        int m = m0 + wm + mt * 16 + (l >> 4) * 4;
#pragma unroll
        for (int nt = 0; nt < 4; ++nt) {
            int n = n0 + wn + nt * 16 + (l & 15);
            float bv = bias[n];
#pragma unroll
            for (int r = 0; r < 4; ++r) {
                float v = acc[mt][nt][r] + bv;
                if (relu) v = fmaxf(v, 0.f);
                if (Cf) Cf[(size_t)(m + r) * HDIM + n] = v;
                else    Cb[(size_t)(m + r) * HDIM + n] = (short)f2b(v);
            }
        }
    }
}

extern "C" void kernel_launch(void* const* d_in, const int* in_sizes, int n_in,
                              void* d_out, int out_size, void* d_ws, size_t ws_size,
                              hipStream_t stream) {
    const float* x   = (const float*)d_in[0];
    const int*   ei  = (const int*)d_in[1];
    const int*   sel = (const int*)d_in[2];
    const int*   src = ei;
    const int*   dst = ei + EDGES;
    const float* cw1[3] = {(const float*)d_in[4],  (const float*)d_in[8],  (const float*)d_in[12]};
    const float* cb1[3] = {(const float*)d_in[5],  (const float*)d_in[9],  (const float*)d_in[13]};
    const float* cw2[3] = {(const float*)d_in[6],  (const float*)d_in[10], (const float*)d_in[14]};
    const float* cb2[3] = {(const float*)d_in[7],  (const float*)d_in[11], (const float*)d_in[15]};
    const float* fw1 = (const float*)d_in[16];
    const float* fb1 = (const float*)d_in[17];
    const float* fw2 = (const float*)d_in[18];
    const float* fb2 = (const float*)d_in[19];
    float* out = (float*)d_out;

    const size_t MB = 1024 * 1024;
    char* p = (char*)d_ws;
    unsigned int* keys = (unsigned int*)p;                   // 32 MB
    short* U    = (short*)(p + 32 * MB);                     // 16 MB (fp16)
    short* V    = (short*)(p + 48 * MB);                     // 16 MB (fp16)
    short* hb   = (short*)(p + 64 * MB);                     // 16 MB (bf16)
    short* Wall = (short*)(p + 80 * MB);                     // 9 x 0.5 MB conv mats
    short* fw1T = Wall + 9 * 512 * 512;                      // FFN mats
    short* fw2T = fw1T + 512 * 512;
    int*   dstS = (int*)(p + 86 * MB);                       // 1 MB
    int*   srcS = (int*)(p + 87 * MB);                       // 1 MB
    int*   hist = (int*)(p + 88 * MB);                       // 64 KB
    int*   curs = hist + N_NODES;                            // 64 KB
    short* t1b  = (short*)(p + 89 * MB);                     // 4 MB

    // --- sort edges by dst (edges constant across layers) ---
    (void)hipMemsetAsync(hist, 0, N_NODES * sizeof(int), stream);
    hist_kernel<<<EDGES / 256, 256, 0, stream>>>(dst, hist);
    scan_kernel<<<1, 256, 0, stream>>>(hist, curs);
    scatter_kernel<<<EDGES / 256, 256, 0, stream>>>(dst, src, curs, dstS, srcS);

    cvt_bf16_kernel<<<8192, 256, 0, stream>>>(x, hb);
    tr_kernel<<<dim3(16, 16, 2), dim3(32, 8), 0, stream>>>(fw1, fw2, fw1T, fw2T);
    prep_weights_all_kernel<<<dim3(16, 16, 9), dim3(32, 8), 0, stream>>>(
        cw1[0], cw2[0], cw1[1], cw2[1], cw1[2], cw2[2], Wall);
    (void)hipMemsetAsync(keys, 0, 32 * MB, stream);          // layer-0 key init

    for (int l = 0; l < 3; ++l) {
        short* WdT  = Wall + (size_t)(l * 3 + 0) * 512 * 512;
        short* w1bT = Wall + (size_t)(l * 3 + 1) * 512 * 512;
        short* W2T  = Wall + (size_t)(l * 3 + 2) * 512 * 512;
        node_gemm_uv_kernel<<<dim3(128, 4), 256, 0, stream>>>(hb, WdT, w1bT, cb1[l], U, V);
        edge_mfma_kernel<<<8192, 256, 0, stream>>>(U, V, W2T, srcS, dstS, keys);
        decode_kernel<<<(N_NODES * HDIM / 2) / 256, 256, 0, stream>>>(keys, cb2[l], hb);
    }

    // FFN: gather fused into GEMM1's A-stage via sel indirection
    ffn_gemm_kernel<<<dim3(64, 4), 256, 0, stream>>>(hb, sel, fw1T, fb1, t1b, nullptr, 1);
    ffn_gemm_kernel<<<dim3(64, 4), 256, 0, stream>>>(t1b, nullptr, fw2T, fb2, nullptr, out, 0);
}

// Round 11
// 723.003 us; speedup vs baseline: 1.4976x; 1.4976x over previous
//
#include <hip/hip_runtime.h>
#include <hip/hip_bf16.h>

// UCCAEncoder: 3x EdgeConv(max) + FFN + gather. R20:
//  - R19 retried WITHOUT the coalescing confound: W2 stored in MFMA-FRAGMENT
//    ORDER by the prep kernel (per 16-row n-tile x 32-col half-step, 1KB
//    fragment laid out [lane][8]), so the edge kernel's B loads are single
//    fully-coalesced 1KB-per-wave dwordx4 reads straight to registers.
//    R19's failure was 16 lanes striding 1KB (16 lines/instr, L2-issue-bound,
//    291us); the idea under test (B out of LDS -> port 66%->~33%) was never
//    reached. B now: no DMA, no ds_read, no manual vmcnt; 17 barriers
//    (lgkmcnt-only, guarding the 8KB As). LDS = 25KB, (256,3).
//    Decision rule: edge at ~205 with B out of LDS = LDS-port theory dead ->
//    latency-structural floor.
//  - keeps R18: merged+pipelined node GEMM, batched prep, ffn retile+fused
//    gather, decode x2, LDS key-tile epilogue, sorted edges, XCD swizzle.

#define N_NODES 16384
#define EDGES   262144
#define HDIM    512
#define SEQ     2048

typedef __attribute__((ext_vector_type(8))) short short8;
typedef __attribute__((ext_vector_type(8))) _Float16 half8;
typedef __attribute__((ext_vector_type(2))) _Float16 half2v;
typedef __attribute__((ext_vector_type(4))) float f32x4;

__device__ __forceinline__ void gld16(const void* g, void* l) {
    __builtin_amdgcn_global_load_lds(
        (const __attribute__((address_space(1))) void*)g,
        (__attribute__((address_space(3))) void*)l, 16, 0, 0);
}
__device__ __forceinline__ unsigned short f2b(float f) {   // fp32 -> bf16 RNE
    unsigned int x = __float_as_uint(f);
    return (unsigned short)((x + 0x7fffu + ((x >> 16) & 1u)) >> 16);
}
__device__ __forceinline__ unsigned short f2h(float f) {   // fp32 -> fp16 bits
    _Float16 h = (_Float16)f;
    return __builtin_bit_cast(unsigned short, h);
}
// packed fp16: z = max(u+v, 0) (v_pk_add_f16 + v_pk_max_f16)
__device__ __forceinline__ unsigned int zpack_h(unsigned int u, unsigned int v) {
    half2v a = __builtin_bit_cast(half2v, u);
    half2v b = __builtin_bit_cast(half2v, v);
    half2v s = a + b;
    half2v z = {(_Float16)0.f, (_Float16)0.f};
    half2v r = __builtin_elementwise_max(s, z);
    return __builtin_bit_cast(unsigned int, r);
}
// ---- Bk=32 LDS swizzle (node/FFN GEMMs): slot = seg ^ ((row>>1)&3), row stride 64B
__device__ __forceinline__ short8 frag_ld(const short* S, int row, int q) {
    int p = q ^ ((row >> 1) & 3);
    return *(const short8*)(S + row * 32 + p * 8);
}
__device__ __forceinline__ void stage_tile(const short* G, int kc, short* S, int t) {
#pragma unroll
    for (int it = 0; it < 2; ++it) {
        int lin = it * 256 + t;
        int row = lin >> 2, p = lin & 3;
        int q = p ^ ((row >> 1) & 3);
        gld16(G + (size_t)row * HDIM + kc + q * 8, S + lin * 8);
    }
}
// ---- Bk=64 LDS swizzle (edge A tile): row stride 128B = bank wrap ->
//      slot = seg ^ ((row>>1)&7) ^ (row&1); 8 segs of 8 els per row.
__device__ __forceinline__ half8 frag64(const short* S, int row, int q) {
    int p = q ^ ((row >> 1) & 7) ^ (row & 1);
    return *(const half8*)(S + row * 64 + p * 8);
}

// ================= edge sort (counting sort by dst) =================
__global__ __launch_bounds__(256) void hist_kernel(
    const int* __restrict__ dst, int* __restrict__ hist) {
    int idx = blockIdx.x * 256 + threadIdx.x;
    atomicAdd(&hist[dst[idx]], 1);
}
__global__ __launch_bounds__(256) void scan_kernel(
    const int* __restrict__ hist, int* __restrict__ cursor) {
    __shared__ int part[256];
    const int t = threadIdx.x, base = t * 64;
    int sum = 0;
    for (int i = 0; i < 64; ++i) sum += hist[base + i];
    part[t] = sum;
    __syncthreads();
    int run = 0;
    for (int i = 0; i < t; ++i) run += part[i];
    for (int i = 0; i < 64; ++i) {
        int h = hist[base + i];
        cursor[base + i] = run;
        run += h;
    }
}
__global__ __launch_bounds__(256) void scatter_kernel(
    const int* __restrict__ dst, const int* __restrict__ src,
    int* __restrict__ cursor, int* __restrict__ dstS, int* __restrict__ srcS) {
    int idx = blockIdx.x * 256 + threadIdx.x;
    int d = dst[idx];
    int p = atomicAdd(&cursor[d], 1);
    dstS[p] = d;
    srcS[p] = src[idx];
}

// ================= weights / input prep =================
// ALL conv layers batched: grid z = 9 (layer = z/3, which = z%3).
// which==0/1 -> [n][k] transposed bf16. which==2 -> W2 in MFMA-FRAGMENT order:
// frag (ntile = n>>4, hh = k>>5) is 64 lanes x 8 els contiguous;
// lane = (n&15) | (((k>>3)&3)<<4), el = k&7.
__global__ __launch_bounds__(256) void prep_weights_all_kernel(
    const float* __restrict__ w1_0, const float* __restrict__ w2_0,
    const float* __restrict__ w1_1, const float* __restrict__ w2_1,
    const float* __restrict__ w1_2, const float* __restrict__ w2_2,
    short* __restrict__ outbase) {
    __shared__ float tile[32][33];
    const int z = blockIdx.z;
    const int layer = z / 3, which = z % 3;
    const float* w1 = layer == 0 ? w1_0 : (layer == 1 ? w1_1 : w1_2);
    const float* w2 = layer == 0 ? w2_0 : (layer == 1 ? w2_1 : w2_2);
    const int k0 = blockIdx.x * 32, n0 = blockIdx.y * 32;
    const int tx = threadIdx.x, ty = threadIdx.y;
#pragma unroll
    for (int i = 0; i < 4; ++i) {
        int k = k0 + ty + i * 8, n = n0 + tx;
        float v;
        if (which == 0)      v = w1[k * 512 + n] - w1[(k + 512) * 512 + n];
        else if (which == 1) v = w1[(k + 512) * 512 + n];
        else                 v = w2[k * 512 + n];
        tile[ty + i * 8][tx] = v;
    }
    __syncthreads();
    short* out = outbase + (size_t)(layer * 3 + which) * 512 * 512;
#pragma unroll
    for (int i = 0; i < 4; ++i) {
        int n = n0 + ty + i * 8, k = k0 + tx;
        float v = tile[tx][ty + i * 8];
        if (which == 2) {
            int lane = (n & 15) | (((k >> 3) & 3) << 4);
            size_t idx = ((size_t)((n >> 4) * 16 + (k >> 5)) * 64 + lane) * 8 + (k & 7);
            out[idx] = (short)f2h(v);
        } else {
            out[(size_t)n * 512 + k] = (short)f2b(v);
        }
    }
}
// FFN mats (bf16): z=0 fw1, z=1 fw2
__global__ __launch_bounds__(256) void tr_kernel(
    const float* __restrict__ W1, const float* __restrict__ W2,
    short* __restrict__ T1, short* __restrict__ T2) {
    __shared__ float tile[32][33];
    const float* W = blockIdx.z ? W2 : W1;
    short* T = blockIdx.z ? T2 : T1;
    const int k0 = blockIdx.x * 32, n0 = blockIdx.y * 32;
    const int tx = threadIdx.x, ty = threadIdx.y;
#pragma unroll
    for (int i = 0; i < 4; ++i)
        tile[ty + i * 8][tx] = W[(k0 + ty + i * 8) * 512 + n0 + tx];
    __syncthreads();
#pragma unroll
    for (int i = 0; i < 4; ++i)
        T[(size_t)(n0 + ty + i * 8) * 512 + k0 + tx] = (short)f2b(tile[tx][ty + i * 8]);
}
__global__ __launch_bounds__(256) void cvt_bf16_kernel(
    const float* __restrict__ x, short* __restrict__ xb) {
    int idx = blockIdx.x * 256 + threadIdx.x;
    float4 v = ((const float4*)x)[idx];
    uint2 o;
    o.x = (unsigned int)f2b(v.x) | ((unsigned int)f2b(v.y) << 16);
    o.y = (unsigned int)f2b(v.z) | ((unsigned int)f2b(v.w) << 16);
    ((uint2*)xb)[idx] = o;
}

// ========== fused U/V node GEMM, merged + counted-vmcnt dbuf pipeline ==========
__global__ __launch_bounds__(256, 2) void node_gemm_uv_kernel(
    const short* __restrict__ A, const short* __restrict__ WdT,
    const short* __restrict__ w1bT, const float* __restrict__ b1,
    short* __restrict__ U, short* __restrict__ V) {
    __shared__ short As[2][128 * 32];
    __shared__ short Bu[2][128 * 32];
    __shared__ short Bv[2][128 * 32];   // 48 KB total
    const int t = threadIdx.x;
    const int m0 = blockIdx.x * 128, n0 = blockIdx.y * 128;
    const int w = t >> 6, l = t & 63;
    const int wm = (w & 1) * 64, wn = (w >> 1) * 64;
    const short* Ag = A + (size_t)m0 * HDIM;
    const short* Ug = WdT + (size_t)n0 * HDIM;
    const short* Vg = w1bT + (size_t)n0 * HDIM;
    f32x4 aU[4][4] = {}, aV[4][4] = {};
    stage_tile(Ag, 0, As[0], t);
    stage_tile(Ug, 0, Bu[0], t);
    stage_tile(Vg, 0, Bv[0], t);
#pragma unroll
    for (int hh = 0; hh < 16; ++hh) {
        if (hh < 15) {
            const int kc1 = (hh + 1) * 32;
            stage_tile(Ag, kc1, As[(hh + 1) & 1], t);
            stage_tile(Ug, kc1, Bu[(hh + 1) & 1], t);
            stage_tile(Vg, kc1, Bv[(hh + 1) & 1], t);
            asm volatile("s_waitcnt vmcnt(6)" ::: "memory");
        } else {
            asm volatile("s_waitcnt vmcnt(0)" ::: "memory");
        }
        __builtin_amdgcn_s_barrier();
        asm volatile("" ::: "memory");
        const short* Ab = As[hh & 1];
        const short* Bub = Bu[hh & 1];
        const short* Bvb = Bv[hh & 1];
        short8 a[4], bu[4], bv[4];
#pragma unroll
        for (int mt = 0; mt < 4; ++mt) a[mt] = frag_ld(Ab, wm + mt * 16 + (l & 15), l >> 4);
#pragma unroll
        for (int nt = 0; nt < 4; ++nt) {
            bu[nt] = frag_ld(Bub, wn + nt * 16 + (l & 15), l >> 4);
            bv[nt] = frag_ld(Bvb, wn + nt * 16 + (l & 15), l >> 4);
        }
#pragma unroll
        for (int mt = 0; mt < 4; ++mt)
#pragma unroll
            for (int nt = 0; nt < 4; ++nt) {
                aU[mt][nt] = __builtin_amdgcn_mfma_f32_16x16x32_bf16(a[mt], bu[nt], aU[mt][nt], 0, 0, 0);
                aV[mt][nt] = __builtin_amdgcn_mfma_f32_16x16x32_bf16(a[mt], bv[nt], aV[mt][nt], 0, 0, 0);
            }
        asm volatile("" ::: "memory");
        __builtin_amdgcn_s_barrier();
    }
#pragma unroll
    for (int mt = 0; mt < 4; ++mt) {
        int m = m0 + wm + mt * 16 + (l >> 4) * 4;
#pragma unroll
        for (int nt = 0; nt < 4; ++nt) {
            int n = n0 + wn + nt * 16 + (l & 15);
            float bv = b1[n];
#pragma unroll
            for (int r = 0; r < 4; ++r) {
                U[(size_t)(m + r) * HDIM + n] = (short)f2h(aU[mt][nt][r] + bv);
                V[(size_t)(m + r) * HDIM + n] = (short)f2h(aV[mt][nt][r]);
            }
        }
    }
}

// ====== edge GEMM: B direct L2->reg via FRAGMENT-ORDERED W2, A in LDS ======
__device__ __forceinline__ unsigned int fkey(float m) {    // monotone fp32->uint
    unsigned int b = __float_as_uint(m);
    return ((int)b < 0) ? ~b : (b | 0x80000000u);
}
__device__ __forceinline__ void kflush(unsigned int* K, int d, int col, float m) {
    atomicMax(K + (((size_t)d) << 9) + col, fkey(m));
}
__global__ __launch_bounds__(256, 3) void edge_mfma_kernel(
    const short* __restrict__ U, const short* __restrict__ V,
    const short* __restrict__ W2f, const int* __restrict__ srcS,
    const int* __restrict__ dstS, unsigned int* __restrict__ K) {
    __shared__ short As[64 * 64];            // 8 KB (z, fp16, Bk=64, single buf)
    __shared__ unsigned int ktile[16 * 256]; // 16 KB (epilogue key tile)
    __shared__ int sdst[64], ssrc[64];
    const int t = threadIdx.x;
    // XCD swizzle: L%8 = XCD; the 2 n-halves of edge-group g are 8 apart (same XCD).
    const int L  = blockIdx.x;                 // 0..8191
    const int g  = (L >> 4) * 8 + (L & 7);     // edge-group 0..4095 (64 edges each)
    const int nh = (L >> 3) & 1;               // n-half
    const int e0 = g * 64, n0 = nh * 256;
    if (t < 64) { sdst[t] = dstS[e0 + t]; ssrc[t] = srcS[e0 + t]; }
    __syncthreads();
    const int w = t >> 6, l = t & 63;
    const int wnb = w * 64;                    // 64-col slice
    const int lm = l & 15;
    const int arow = t >> 2, s0 = (t & 3) * 2; // thread covers 32B (segs s0,s0+1)
    const int perm = ((arow >> 1) & 7) ^ (arow & 1);
    const int p0 = s0 ^ perm, p1 = (s0 + 1) ^ perm;
    const short* up = U + (((size_t)sdst[arow]) << 9) + s0 * 8;
    const short* vp = V + (((size_t)ssrc[arow]) << 9) + s0 * 8;
    // fragment-ordered B: frag (ntile, hh) at W2f + ntile*8192 + hh*512, lane-major.
    // Each load below is one fully-coalesced 1KB-per-wave dwordx4.
    const short* bp = W2f + (size_t)((n0 + wnb) >> 4) * 8192 + (size_t)l * 8;
    unsigned int* As_u = (unsigned int*)As;
    f32x4 acc[4][4] = {};
    half8 bc[4], bn[4];
    uint4 pu0, pu1, pv0, pv1;
    // ---- prologue: B(0), A(0), zpack->As(0), A(1), barrier ----
#pragma unroll
    for (int nt = 0; nt < 4; ++nt) bc[nt] = *(const half8*)(bp + nt * 8192);
    pu0 = *(const uint4*)(up);      pu1 = *(const uint4*)(up + 8);
    pv0 = *(const uint4*)(vp);      pv1 = *(const uint4*)(vp + 8);
    {
        uint4 z0, z1;
        z0.x = zpack_h(pu0.x, pv0.x); z0.y = zpack_h(pu0.y, pv0.y);
        z0.z = zpack_h(pu0.z, pv0.z); z0.w = zpack_h(pu0.w, pv0.w);
        z1.x = zpack_h(pu1.x, pv1.x); z1.y = zpack_h(pu1.y, pv1.y);
        z1.z = zpack_h(pu1.z, pv1.z); z1.w = zpack_h(pu1.w, pv1.w);
        *(uint4*)(As_u + arow * 32 + p0 * 4) = z0;
        *(uint4*)(As_u + arow * 32 + p1 * 4) = z1;
    }
    pu0 = *(const uint4*)(up + 64); pu1 = *(const uint4*)(up + 72);
    pv0 = *(const uint4*)(vp + 64); pv1 = *(const uint4*)(vp + 72);
    asm volatile("s_waitcnt lgkmcnt(0)" ::: "memory");
    __builtin_amdgcn_s_barrier();
    asm volatile("" ::: "memory");
    // ---- 8 K-steps; step j: half-steps h0=2j (B=bc), h1=2j+1 (B=bn).
    // B(h+1) issued before h's 16-MFMA cluster (~330cy) -> L2 latency hidden.
    // Compiler inserts exact counted vmcnt for bc/bn/pu/pv (plain reg loads);
    // raw barriers (lgkmcnt-only) guard the single-buffered As.
#pragma unroll
    for (int j = 0; j < 8; ++j) {
        const int h1 = 2 * j + 1;
        // issue B(h1)
#pragma unroll
        for (int nt = 0; nt < 4; ++nt)
            bn[nt] = *(const half8*)(bp + nt * 8192 + h1 * 512);
        // even half-step: A segs q = l>>4
        __builtin_amdgcn_s_setprio(1);
#pragma unroll
        for (int mt = 0; mt < 4; ++mt) {
            half8 a = frag64(As, mt * 16 + lm, (l >> 4));
#pragma unroll
            for (int nt = 0; nt < 4; ++nt)
                acc[mt][nt] = __builtin_amdgcn_mfma_f32_16x16x32_f16(a, bc[nt], acc[mt][nt], 0, 0, 0);
        }
        __builtin_amdgcn_s_setprio(0);
        // issue B(2j+2) for next iteration
        if (j < 7) {
#pragma unroll
            for (int nt = 0; nt < 4; ++nt)
                bc[nt] = *(const half8*)(bp + nt * 8192 + (h1 + 1) * 512);
        }
        // odd half-step: A segs q = 4 + (l>>4)
        __builtin_amdgcn_s_setprio(1);
#pragma unroll
        for (int mt = 0; mt < 4; ++mt) {
            half8 a = frag64(As, mt * 16 + lm, 4 + (l >> 4));
#pragma unroll
            for (int nt = 0; nt < 4; ++nt)
                acc[mt][nt] = __builtin_amdgcn_mfma_f32_16x16x32_f16(a, bn[nt], acc[mt][nt], 0, 0, 0);
        }
        __builtin_amdgcn_s_setprio(0);
        asm volatile("s_waitcnt lgkmcnt(0)" ::: "memory");
        __builtin_amdgcn_s_barrier();           // WAR: all waves done reading As(j)
        asm volatile("" ::: "memory");
        if (j < 7) {
            // zpack A(j+1) -> As(j+1); reload pu/pv <- A(j+2)
            uint4 z0, z1;
            z0.x = zpack_h(pu0.x, pv0.x); z0.y = zpack_h(pu0.y, pv0.y);
            z0.z = zpack_h(pu0.z, pv0.z); z0.w = zpack_h(pu0.w, pv0.w);
            z1.x = zpack_h(pu1.x, pv1.x); z1.y = zpack_h(pu1.y, pv1.y);
            z1.z = zpack_h(pu1.z, pv1.z); z1.w = zpack_h(pu1.w, pv1.w);
            *(uint4*)(As_u + arow * 32 + p0 * 4) = z0;
            *(uint4*)(As_u + arow * 32 + p1 * 4) = z1;
            if (j < 6) {
                const int kn = (j + 2) * 64;
                pu0 = *(const uint4*)(up + kn);      pu1 = *(const uint4*)(up + kn + 8);
                pv0 = *(const uint4*)(vp + kn);      pv1 = *(const uint4*)(vp + kn + 8);
            }
            asm volatile("s_waitcnt lgkmcnt(0)" ::: "memory");
            __builtin_amdgcn_s_barrier();       // RAW: As(j+1) visible to all
            asm volatile("" ::: "memory");
        }
    }
    // ===== epilogue: segment-max pre-reduced in LDS key tile, sparse flush =====
    const int dbase = sdst[0];
    const int drange = sdst[63] - dbase + 1;
    if (drange <= 16) {
#pragma unroll
        for (int i = 0; i < 16; ++i) ktile[i * 256 + t] = 0u;   // zero tile
        __syncthreads();
#pragma unroll
        for (int mt = 0; mt < 4; ++mt) {
            int base = mt * 16 + (l >> 4) * 4;
            int d0 = sdst[base], d1 = sdst[base + 1], d2 = sdst[base + 2], d3 = sdst[base + 3];
            int r0 = d0 - dbase, r1 = d1 - dbase, r2 = d2 - dbase, r3 = d3 - dbase;
#pragma unroll
            for (int nt = 0; nt < 4; ++nt) {
                int colb = wnb + nt * 16 + lm;
                f32x4 a = acc[mt][nt];
                float m = a[0];
                if (d1 == d0) m = fmaxf(m, a[1]);
                else { atomicMax(ktile + r0 * 256 + colb, fkey(m)); m = a[1]; }
                if (d2 == d1) m = fmaxf(m, a[2]);
                else { atomicMax(ktile + r1 * 256 + colb, fkey(m)); m = a[2]; }
                if (d3 == d2) m = fmaxf(m, a[3]);
                else { atomicMax(ktile + r2 * 256 + colb, fkey(m)); m = a[3]; }
                atomicMax(ktile + r3 * 256 + colb, fkey(m));
            }
        }
        __syncthreads();
        // flush non-empty rows: thread t owns column n0+t across all rows
#pragma unroll 4
        for (int r = 0; r < 16; ++r) {
            if (r < drange) {
                unsigned int kv = ktile[r * 256 + t];
                if (kv) atomicMax(K + (((size_t)(dbase + r)) << 9) + n0 + t, kv);
            }
        }
    } else {
        // fallback (degenerate range): direct run-compressed global flushes
#pragma unroll
        for (int mt = 0; mt < 4; ++mt) {
            int base = mt * 16 + (l >> 4) * 4;
            int d0 = sdst[base], d1 = sdst[base + 1], d2 = sdst[base + 2], d3 = sdst[base + 3];
#pragma unroll
            for (int nt = 0; nt < 4; ++nt) {
                int col = n0 + wnb + nt * 16 + lm;
                f32x4 a = acc[mt][nt];
                float m = a[0];
                if (d1 == d0) m = fmaxf(m, a[1]); else { kflush(K, d0, col, m); m = a[1]; }
                if (d2 == d1) m = fmaxf(m, a[2]); else { kflush(K, d1, col, m); m = a[2]; }
                if (d3 == d2) m = fmaxf(m, a[3]); else { kflush(K, d2, col, m); m = a[3]; }
                kflush(K, d3, col, m);
            }
        }
    }
}

// ======= decode keys -> h bf16 (x2 vectorized); re-zero keys for next layer =======
__global__ __launch_bounds__(256) void decode_kernel(
    unsigned int* __restrict__ K, const float* __restrict__ b2,
    short* __restrict__ hb) {
    int idx = blockIdx.x * 256 + threadIdx.x;          // 2 keys per thread
    uint2 k = ((uint2*)K)[idx];
    uint2 zz = {0u, 0u};
    ((uint2*)K)[idx] = zz;                             // init for next layer
    int c = (idx << 1) & (HDIM - 1);
    float v0 = 0.f, v1 = 0.f;
    if (k.x != 0u) {
        unsigned int b = (k.x & 0x80000000u) ? (k.x ^ 0x80000000u) : ~k.x;
        v0 = __uint_as_float(b) + b2[c];
    }
    if (k.y != 0u) {
        unsigned int b = (k.y & 0x80000000u) ? (k.y ^ 0x80000000u) : ~k.y;
        v1 = __uint_as_float(b) + b2[c + 1];
    }
    unsigned int o = (unsigned int)f2b(fmaxf(v0, 0.f))
                   | ((unsigned int)f2b(fmaxf(v1, 0.f)) << 16);
    ((unsigned int*)hb)[idx] = o;
}

// ========= MFMA GEMM (FFN), 64x128 tiles, optional sel-gather on A =========
__global__ __launch_bounds__(256) void ffn_gemm_kernel(
    const short* __restrict__ A, const int* __restrict__ sel,
    const short* __restrict__ Wt, const float* __restrict__ bias,
    short* __restrict__ Cb, float* __restrict__ Cf, int relu) {
    __shared__ short As[64 * 32];      // 4 KB
    __shared__ short Bs[128 * 32];     // 8 KB
    const int t = threadIdx.x;
    const int m0 = blockIdx.x * 64, n0 = blockIdx.y * 128;
    const int w = t >> 6, l = t & 63;
    const int wm = (w & 1) * 32, wn = (w >> 1) * 64;
    const int srow = t >> 2, sp = t & 3;
    const int sq = sp ^ ((srow >> 1) & 3);
    const short* ap;
    if (sel) {                                   // fused gather: row -> hb row
        int gr = m0 + srow;                      // 0..4095
        ap = A + (((size_t)((gr >> 9) * SEQ + sel[gr])) << 9);
    } else {
        ap = A + (size_t)(m0 + srow) * HDIM;
    }
    f32x4 acc[2][4] = {};
    for (int kc = 0; kc < HDIM; kc += 32) {
        gld16(ap + kc + sq * 8, As + t * 8);
        stage_tile(Wt + (size_t)n0 * HDIM, kc, Bs, t);
        __syncthreads();
        short8 a[2], b[4];
#pragma unroll
        for (int mt = 0; mt < 2; ++mt) a[mt] = frag_ld(As, wm + mt * 16 + (l & 15), l >> 4);
#pragma unroll
        for (int nt = 0; nt < 4; ++nt) b[nt] = frag_ld(Bs, wn + nt * 16 + (l & 15), l >> 4);
#pragma unroll
        for (int mt = 0; mt < 2; ++mt)
#pragma unroll
            for (int nt = 0; nt < 4; ++nt)
                acc[mt][nt] = __builtin_amdgcn_mfma_f32_16x16x32_bf16(a[mt], b[nt], acc[mt][nt], 0, 0, 0);
        __syncthreads();
    }
#pragma unroll
    for (int mt = 0; mt < 2; ++mt) {
        int m = m0 + wm + mt * 16 + (l >> 4) * 4;
#pragma unroll
        for (int nt = 0; nt < 4; ++nt) {
            int n = n0 + wn + nt * 16 + (l & 15);
            float bv = bias[n];
#pragma unroll
            for (int r = 0; r < 4; ++r) {
                float v = acc[mt][nt][r] + bv;
                if (relu) v = fmaxf(v, 0.f);
                if (Cf) Cf[(size_t)(m + r) * HDIM + n] = v;
                else    Cb[(size_t)(m + r) * HDIM + n] = (short)f2b(v);
            }
        }
    }
}

extern "C" void kernel_launch(void* const* d_in, const int* in_sizes, int n_in,
                              void* d_out, int out_size, void* d_ws, size_t ws_size,
                              hipStream_t stream) {
    const float* x   = (const float*)d_in[0];
    const int*   ei  = (const int*)d_in[1];
    const int*   sel = (const int*)d_in[2];
    const int*   src = ei;
    const int*   dst = ei + EDGES;
    const float* cw1[3] = {(const float*)d_in[4],  (const float*)d_in[8],  (const float*)d_in[12]};
    const float* cb1[3] = {(const float*)d_in[5],  (const float*)d_in[9],  (const float*)d_in[13]};
    const float* cw2[3] = {(const float*)d_in[6],  (const float*)d_in[10], (const float*)d_in[14]};
    const float* cb2[3] = {(const float*)d_in[7],  (const float*)d_in[11], (const float*)d_in[15]};
    const float* fw1 = (const float*)d_in[16];
    const float* fb1 = (const float*)d_in[17];
    const float* fw2 = (const float*)d_in[18];
    const float* fb2 = (const float*)d_in[19];
    float* out = (float*)d_out;

    const size_t MB = 1024 * 1024;
    char* p = (char*)d_ws;
    unsigned int* keys = (unsigned int*)p;                   // 32 MB
    short* U    = (short*)(p + 32 * MB);                     // 16 MB (fp16)
    short* V    = (short*)(p + 48 * MB);                     // 16 MB (fp16)
    short* hb   = (short*)(p + 64 * MB);                     // 16 MB (bf16)
    short* Wall = (short*)(p + 80 * MB);                     // 9 x 0.5 MB conv mats
    short* fw1T = Wall + 9 * 512 * 512;                      // FFN mats
    short* fw2T = fw1T + 512 * 512;
    int*   dstS = (int*)(p + 86 * MB);                       // 1 MB
    int*   srcS = (int*)(p + 87 * MB);                       // 1 MB
    int*   hist = (int*)(p + 88 * MB);                       // 64 KB
    int*   curs = hist + N_NODES;                            // 64 KB
    short* t1b  = (short*)(p + 89 * MB);                     // 4 MB

    // --- sort edges by dst (edges constant across layers) ---
    (void)hipMemsetAsync(hist, 0, N_NODES * sizeof(int), stream);
    hist_kernel<<<EDGES / 256, 256, 0, stream>>>(dst, hist);
    scan_kernel<<<1, 256, 0, stream>>>(hist, curs);
    scatter_kernel<<<EDGES / 256, 256, 0, stream>>>(dst, src, curs, dstS, srcS);

    cvt_bf16_kernel<<<8192, 256, 0, stream>>>(x, hb);
    tr_kernel<<<dim3(16, 16, 2), dim3(32, 8), 0, stream>>>(fw1, fw2, fw1T, fw2T);
    prep_weights_all_kernel<<<dim3(16, 16, 9), dim3(32, 8), 0, stream>>>(
        cw1[0], cw2[0], cw1[1], cw2[1], cw1[2], cw2[2], Wall);
    (void)hipMemsetAsync(keys, 0, 32 * MB, stream);          // layer-0 key init

    for (int l = 0; l < 3; ++l) {
        short* WdT  = Wall + (size_t)(l * 3 + 0) * 512 * 512;
        short* w1bT = Wall + (size_t)(l * 3 + 1) * 512 * 512;
        short* W2f  = Wall + (size_t)(l * 3 + 2) * 512 * 512;
        node_gemm_uv_kernel<<<dim3(128, 4), 256, 0, stream>>>(hb, WdT, w1bT, cb1[l], U, V);
        edge_mfma_kernel<<<8192, 256, 0, stream>>>(U, V, W2f, srcS, dstS, keys);
        decode_kernel<<<(N_NODES * HDIM / 2) / 256, 256, 0, stream>>>(keys, cb2[l], hb);
    }

    // FFN: gather fused into GEMM1's A-stage via sel indirection
    ffn_gemm_kernel<<<dim3(64, 4), 256, 0, stream>>>(hb, sel, fw1T, fb1, t1b, nullptr, 1);
    ffn_gemm_kernel<<<dim3(64, 4), 256, 0, stream>>>(t1b, nullptr, fw2T, fb2, nullptr, out, 0);
}

// Round 12
// 717.235 us; speedup vs baseline: 1.5096x; 1.0080x over previous
//
#include <hip/hip_runtime.h>
#include <hip/hip_bf16.h>

// UCCAEncoder: 3x EdgeConv(max) + FFN + gather. R21:
//  - edge kernel: UNCHANGED from R20 (150.5us, MfmaUtil 41.6 -- B direct from
//    L2 via fragment-ordered W2 confirmed the LDS-port theory, -26%).
//  - node_gemm_uv: same recipe ported. ALL THREE conv mats now stored in
//    MFMA-fragment order by prep; node GEMM loads B_U/B_V frags direct
//    L2->reg (1KB coalesced per wave-frag), A stays in LDS (16KB dbuf).
//    Pipeline mirrors edge: B(hh+1) prefetched into parity regs bu2/bv2
//    (compile-time indexed), A-DMA counted: steady queue entering = B_V(hh):4;
//    end-of-step vmcnt(4) drains {B_U(hh+1), A(hh+1)}, leaves B_V(hh+1) in
//    flight; prologue vmcnt(8); ONE barrier/step (16 vs 32). LDS 48->16KB.
//  - keeps: batched frag-order prep, ffn retile+fused gather, decode x2,
//    LDS key-tile edge epilogue, sorted edges, XCD swizzle.

#define N_NODES 16384
#define EDGES   262144
#define HDIM    512
#define SEQ     2048

typedef __attribute__((ext_vector_type(8))) short short8;
typedef __attribute__((ext_vector_type(8))) _Float16 half8;
typedef __attribute__((ext_vector_type(2))) _Float16 half2v;
typedef __attribute__((ext_vector_type(4))) float f32x4;

__device__ __forceinline__ void gld16(const void* g, void* l) {
    __builtin_amdgcn_global_load_lds(
        (const __attribute__((address_space(1))) void*)g,
        (__attribute__((address_space(3))) void*)l, 16, 0, 0);
}
__device__ __forceinline__ unsigned short f2b(float f) {   // fp32 -> bf16 RNE
    unsigned int x = __float_as_uint(f);
    return (unsigned short)((x + 0x7fffu + ((x >> 16) & 1u)) >> 16);
}
__device__ __forceinline__ unsigned short f2h(float f) {   // fp32 -> fp16 bits
    _Float16 h = (_Float16)f;
    return __builtin_bit_cast(unsigned short, h);
}
// packed fp16: z = max(u+v, 0) (v_pk_add_f16 + v_pk_max_f16)
__device__ __forceinline__ unsigned int zpack_h(unsigned int u, unsigned int v) {
    half2v a = __builtin_bit_cast(half2v, u);
    half2v b = __builtin_bit_cast(half2v, v);
    half2v s = a + b;
    half2v z = {(_Float16)0.f, (_Float16)0.f};
    half2v r = __builtin_elementwise_max(s, z);
    return __builtin_bit_cast(unsigned int, r);
}
// ---- Bk=32 LDS swizzle (A tiles / FFN): slot = seg ^ ((row>>1)&3), row stride 64B
__device__ __forceinline__ short8 frag_ld(const short* S, int row, int q) {
    int p = q ^ ((row >> 1) & 3);
    return *(const short8*)(S + row * 32 + p * 8);
}
__device__ __forceinline__ void stage_tile(const short* G, int kc, short* S, int t) {
#pragma unroll
    for (int it = 0; it < 2; ++it) {
        int lin = it * 256 + t;
        int row = lin >> 2, p = lin & 3;
        int q = p ^ ((row >> 1) & 3);
        gld16(G + (size_t)row * HDIM + kc + q * 8, S + lin * 8);
    }
}
// ---- Bk=64 LDS swizzle (edge A tile): row stride 128B = bank wrap ->
//      slot = seg ^ ((row>>1)&7) ^ (row&1); 8 segs of 8 els per row.
__device__ __forceinline__ half8 frag64(const short* S, int row, int q) {
    int p = q ^ ((row >> 1) & 7) ^ (row & 1);
    return *(const half8*)(S + row * 64 + p * 8);
}

// ================= edge sort (counting sort by dst) =================
__global__ __launch_bounds__(256) void hist_kernel(
    const int* __restrict__ dst, int* __restrict__ hist) {
    int idx = blockIdx.x * 256 + threadIdx.x;
    atomicAdd(&hist[dst[idx]], 1);
}
__global__ __launch_bounds__(256) void scan_kernel(
    const int* __restrict__ hist, int* __restrict__ cursor) {
    __shared__ int part[256];
    const int t = threadIdx.x, base = t * 64;
    int sum = 0;
    for (int i = 0; i < 64; ++i) sum += hist[base + i];
    part[t] = sum;
    __syncthreads();
    int run = 0;
    for (int i = 0; i < t; ++i) run += part[i];
    for (int i = 0; i < 64; ++i) {
        int h = hist[base + i];
        cursor[base + i] = run;
        run += h;
    }
}
__global__ __launch_bounds__(256) void scatter_kernel(
    const int* __restrict__ dst, const int* __restrict__ src,
    int* __restrict__ cursor, int* __restrict__ dstS, int* __restrict__ srcS) {
    int idx = blockIdx.x * 256 + threadIdx.x;
    int d = dst[idx];
    int p = atomicAdd(&cursor[d], 1);
    dstS[p] = d;
    srcS[p] = src[idx];
}

// ================= weights / input prep =================
// ALL conv layers batched: grid z = 9 (layer = z/3, which = z%3).
// ALL mats in MFMA-FRAGMENT order: frag (ntile=n>>4, kstep=k>>5) is 64 lanes
// x 8 els contiguous; lane = (n&15)|(((k>>3)&3)<<4), el = k&7.
// which 0/1 -> bf16 (node B mats), which 2 -> fp16 (edge B mat).
__global__ __launch_bounds__(256) void prep_weights_all_kernel(
    const float* __restrict__ w1_0, const float* __restrict__ w2_0,
    const float* __restrict__ w1_1, const float* __restrict__ w2_1,
    const float* __restrict__ w1_2, const float* __restrict__ w2_2,
    short* __restrict__ outbase) {
    __shared__ float tile[32][33];
    const int z = blockIdx.z;
    const int layer = z / 3, which = z % 3;
    const float* w1 = layer == 0 ? w1_0 : (layer == 1 ? w1_1 : w1_2);
    const float* w2 = layer == 0 ? w2_0 : (layer == 1 ? w2_1 : w2_2);
    const int k0 = blockIdx.x * 32, n0 = blockIdx.y * 32;
    const int tx = threadIdx.x, ty = threadIdx.y;
#pragma unroll
    for (int i = 0; i < 4; ++i) {
        int k = k0 + ty + i * 8, n = n0 + tx;
        float v;
        if (which == 0)      v = w1[k * 512 + n] - w1[(k + 512) * 512 + n];
        else if (which == 1) v = w1[(k + 512) * 512 + n];
        else                 v = w2[k * 512 + n];
        tile[ty + i * 8][tx] = v;
    }
    __syncthreads();
    short* out = outbase + (size_t)(layer * 3 + which) * 512 * 512;
#pragma unroll
    for (int i = 0; i < 4; ++i) {
        int n = n0 + ty + i * 8, k = k0 + tx;
        float v = tile[tx][ty + i * 8];
        int lane = (n & 15) | (((k >> 3) & 3) << 4);
        size_t idx = ((size_t)((n >> 4) * 16 + (k >> 5)) * 64 + lane) * 8 + (k & 7);
        out[idx] = (short)(which == 2 ? f2h(v) : f2b(v));
    }
}
// FFN mats (bf16): z=0 fw1, z=1 fw2
__global__ __launch_bounds__(256) void tr_kernel(
    const float* __restrict__ W1, const float* __restrict__ W2,
    short* __restrict__ T1, short* __restrict__ T2) {
    __shared__ float tile[32][33];
    const float* W = blockIdx.z ? W2 : W1;
    short* T = blockIdx.z ? T2 : T1;
    const int k0 = blockIdx.x * 32, n0 = blockIdx.y * 32;
    const int tx = threadIdx.x, ty = threadIdx.y;
#pragma unroll
    for (int i = 0; i < 4; ++i)
        tile[ty + i * 8][tx] = W[(k0 + ty + i * 8) * 512 + n0 + tx];
    __syncthreads();
#pragma unroll
    for (int i = 0; i < 4; ++i)
        T[(size_t)(n0 + ty + i * 8) * 512 + k0 + tx] = (short)f2b(tile[tx][ty + i * 8]);
}
__global__ __launch_bounds__(256) void cvt_bf16_kernel(
    const float* __restrict__ x, short* __restrict__ xb) {
    int idx = blockIdx.x * 256 + threadIdx.x;
    float4 v = ((const float4*)x)[idx];
    uint2 o;
    o.x = (unsigned int)f2b(v.x) | ((unsigned int)f2b(v.y) << 16);
    o.y = (unsigned int)f2b(v.z) | ((unsigned int)f2b(v.w) << 16);
    ((uint2*)xb)[idx] = o;
}

// ========== fused U/V node GEMM: B direct L2->reg (frag order), A LDS dbuf ==========
// grid (128,4), 256 thr, 4 waves (2m x 2n), per-wave 64x64 per mat.
// Steady vm queue entering step hh: B_V(hh):4. End-of-step vmcnt(4) drains
// {B_U(hh+1), A(hh+1)}, leaves B_V(hh+1). One barrier/step (As dbuf).
__global__ __launch_bounds__(256, 2) void node_gemm_uv_kernel(
    const short* __restrict__ A, const short* __restrict__ WdF,
    const short* __restrict__ w1bF, const float* __restrict__ b1,
    short* __restrict__ U, short* __restrict__ V) {
    __shared__ short As[2][128 * 32];   // 16 KB
    const int t = threadIdx.x;
    const int m0 = blockIdx.x * 128, n0 = blockIdx.y * 128;
    const int w = t >> 6, l = t & 63;
    const int wm = (w & 1) * 64, wn = (w >> 1) * 64;
    const short* Ag = A + (size_t)m0 * HDIM;
    const short* bpU = WdF + (size_t)((n0 + wn) >> 4) * 8192 + (size_t)l * 8;
    const short* bpV = w1bF + (size_t)((n0 + wn) >> 4) * 8192 + (size_t)l * 8;
    f32x4 aU[4][4] = {}, aV[4][4] = {};
    short8 bu2[2][4], bv2[2][4];
    // prologue: A(0) DMA (2 ops), B_U(0) (4), B_V(0) (4) -> vmcnt(8) drains A(0)
    stage_tile(Ag, 0, As[0], t);
#pragma unroll
    for (int nt = 0; nt < 4; ++nt) bu2[0][nt] = *(const short8*)(bpU + nt * 8192);
#pragma unroll
    for (int nt = 0; nt < 4; ++nt) bv2[0][nt] = *(const short8*)(bpV + nt * 8192);
    asm volatile("s_waitcnt vmcnt(8)" ::: "memory");
    __builtin_amdgcn_s_barrier();
    asm volatile("" ::: "memory");
#pragma unroll
    for (int hh = 0; hh < 16; ++hh) {
        short8 a[4];
#pragma unroll
        for (int mt = 0; mt < 4; ++mt)
            a[mt] = frag_ld(As[hh & 1], wm + mt * 16 + (l & 15), l >> 4);
        if (hh < 15) {
            // issue B_U(hh+1) + A(hh+1) DMA; fence pins them before MFMA-U
#pragma unroll
            for (int nt = 0; nt < 4; ++nt)
                bu2[(hh + 1) & 1][nt] = *(const short8*)(bpU + nt * 8192 + (hh + 1) * 512);
            stage_tile(Ag, (hh + 1) * 32, As[(hh + 1) & 1], t);
            asm volatile("" ::: "memory");
        }
        __builtin_amdgcn_s_setprio(1);
#pragma unroll
        for (int mt = 0; mt < 4; ++mt)
#pragma unroll
            for (int nt = 0; nt < 4; ++nt)
                aU[mt][nt] = __builtin_amdgcn_mfma_f32_16x16x32_bf16(a[mt], bu2[hh & 1][nt], aU[mt][nt], 0, 0, 0);
        __builtin_amdgcn_s_setprio(0);
        if (hh < 15) {
#pragma unroll
            for (int nt = 0; nt < 4; ++nt)
                bv2[(hh + 1) & 1][nt] = *(const short8*)(bpV + nt * 8192 + (hh + 1) * 512);
        }
        __builtin_amdgcn_s_setprio(1);
#pragma unroll
        for (int mt = 0; mt < 4; ++mt)
#pragma unroll
            for (int nt = 0; nt < 4; ++nt)
                aV[mt][nt] = __builtin_amdgcn_mfma_f32_16x16x32_bf16(a[mt], bv2[hh & 1][nt], aV[mt][nt], 0, 0, 0);
        __builtin_amdgcn_s_setprio(0);
        if (hh < 15) {
            // drain B_U(hh+1)+A(hh+1); keep B_V(hh+1) in flight; sync As dbuf
            asm volatile("s_waitcnt vmcnt(4) lgkmcnt(0)" ::: "memory");
            __builtin_amdgcn_s_barrier();
            asm volatile("" ::: "memory");
        }
    }
#pragma unroll
    for (int mt = 0; mt < 4; ++mt) {
        int m = m0 + wm + mt * 16 + (l >> 4) * 4;
#pragma unroll
        for (int nt = 0; nt < 4; ++nt) {
            int n = n0 + wn + nt * 16 + (l & 15);
            float bv = b1[n];
#pragma unroll
            for (int r = 0; r < 4; ++r) {
                U[(size_t)(m + r) * HDIM + n] = (short)f2h(aU[mt][nt][r] + bv);
                V[(size_t)(m + r) * HDIM + n] = (short)f2h(aV[mt][nt][r]);
            }
        }
    }
}

// ====== edge GEMM (R20 exact): B direct L2->reg via frag-ordered W2, A in LDS ======
__device__ __forceinline__ unsigned int fkey(float m) {    // monotone fp32->uint
    unsigned int b = __float_as_uint(m);
    return ((int)b < 0) ? ~b : (b | 0x80000000u);
}
__device__ __forceinline__ void kflush(unsigned int* K, int d, int col, float m) {
    atomicMax(K + (((size_t)d) << 9) + col, fkey(m));
}
__global__ __launch_bounds__(256, 3) void edge_mfma_kernel(
    const short* __restrict__ U, const short* __restrict__ V,
    const short* __restrict__ W2f, const int* __restrict__ srcS,
    const int* __restrict__ dstS, unsigned int* __restrict__ K) {
    __shared__ short As[64 * 64];            // 8 KB (z, fp16, Bk=64, single buf)
    __shared__ unsigned int ktile[16 * 256]; // 16 KB (epilogue key tile)
    __shared__ int sdst[64], ssrc[64];
    const int t = threadIdx.x;
    // XCD swizzle: L%8 = XCD; the 2 n-halves of edge-group g are 8 apart (same XCD).
    const int L  = blockIdx.x;                 // 0..8191
    const int g  = (L >> 4) * 8 + (L & 7);     // edge-group 0..4095 (64 edges each)
    const int nh = (L >> 3) & 1;               // n-half
    const int e0 = g * 64, n0 = nh * 256;
    if (t < 64) { sdst[t] = dstS[e0 + t]; ssrc[t] = srcS[e0 + t]; }
    __syncthreads();
    const int w = t >> 6, l = t & 63;
    const int wnb = w * 64;                    // 64-col slice
    const int lm = l & 15;
    const int arow = t >> 2, s0 = (t & 3) * 2; // thread covers 32B (segs s0,s0+1)
    const int perm = ((arow >> 1) & 7) ^ (arow & 1);
    const int p0 = s0 ^ perm, p1 = (s0 + 1) ^ perm;
    const short* up = U + (((size_t)sdst[arow]) << 9) + s0 * 8;
    const short* vp = V + (((size_t)ssrc[arow]) << 9) + s0 * 8;
    // fragment-ordered B: frag (ntile, hh) at W2f + ntile*8192 + hh*512, lane-major.
    const short* bp = W2f + (size_t)((n0 + wnb) >> 4) * 8192 + (size_t)l * 8;
    unsigned int* As_u = (unsigned int*)As;
    f32x4 acc[4][4] = {};
    half8 bc[4], bn[4];
    uint4 pu0, pu1, pv0, pv1;
    // ---- prologue: B(0), A(0), zpack->As(0), A(1), barrier ----
#pragma unroll
    for (int nt = 0; nt < 4; ++nt) bc[nt] = *(const half8*)(bp + nt * 8192);
    pu0 = *(const uint4*)(up);      pu1 = *(const uint4*)(up + 8);
    pv0 = *(const uint4*)(vp);      pv1 = *(const uint4*)(vp + 8);
    {
        uint4 z0, z1;
        z0.x = zpack_h(pu0.x, pv0.x); z0.y = zpack_h(pu0.y, pv0.y);
        z0.z = zpack_h(pu0.z, pv0.z); z0.w = zpack_h(pu0.w, pv0.w);
        z1.x = zpack_h(pu1.x, pv1.x); z1.y = zpack_h(pu1.y, pv1.y);
        z1.z = zpack_h(pu1.z, pv1.z); z1.w = zpack_h(pu1.w, pv1.w);
        *(uint4*)(As_u + arow * 32 + p0 * 4) = z0;
        *(uint4*)(As_u + arow * 32 + p1 * 4) = z1;
    }
    pu0 = *(const uint4*)(up + 64); pu1 = *(const uint4*)(up + 72);
    pv0 = *(const uint4*)(vp + 64); pv1 = *(const uint4*)(vp + 72);
    asm volatile("s_waitcnt lgkmcnt(0)" ::: "memory");
    __builtin_amdgcn_s_barrier();
    asm volatile("" ::: "memory");
    // ---- 8 K-steps; step j: half-steps h0=2j (B=bc), h1=2j+1 (B=bn).
#pragma unroll
    for (int j = 0; j < 8; ++j) {
        const int h1 = 2 * j + 1;
#pragma unroll
        for (int nt = 0; nt < 4; ++nt)
            bn[nt] = *(const half8*)(bp + nt * 8192 + h1 * 512);
        __builtin_amdgcn_s_setprio(1);
#pragma unroll
        for (int mt = 0; mt < 4; ++mt) {
            half8 a = frag64(As, mt * 16 + lm, (l >> 4));
#pragma unroll
            for (int nt = 0; nt < 4; ++nt)
                acc[mt][nt] = __builtin_amdgcn_mfma_f32_16x16x32_f16(a, bc[nt], acc[mt][nt], 0, 0, 0);
        }
        __builtin_amdgcn_s_setprio(0);
        if (j < 7) {
#pragma unroll
            for (int nt = 0; nt < 4; ++nt)
                bc[nt] = *(const half8*)(bp + nt * 8192 + (h1 + 1) * 512);
        }
        __builtin_amdgcn_s_setprio(1);
#pragma unroll
        for (int mt = 0; mt < 4; ++mt) {
            half8 a = frag64(As, mt * 16 + lm, 4 + (l >> 4));
#pragma unroll
            for (int nt = 0; nt < 4; ++nt)
                acc[mt][nt] = __builtin_amdgcn_mfma_f32_16x16x32_f16(a, bn[nt], acc[mt][nt], 0, 0, 0);
        }
        __builtin_amdgcn_s_setprio(0);
        asm volatile("s_waitcnt lgkmcnt(0)" ::: "memory");
        __builtin_amdgcn_s_barrier();           // WAR: all waves done reading As(j)
        asm volatile("" ::: "memory");
        if (j < 7) {
            uint4 z0, z1;
            z0.x = zpack_h(pu0.x, pv0.x); z0.y = zpack_h(pu0.y, pv0.y);
            z0.z = zpack_h(pu0.z, pv0.z); z0.w = zpack_h(pu0.w, pv0.w);
            z1.x = zpack_h(pu1.x, pv1.x); z1.y = zpack_h(pu1.y, pv1.y);
            z1.z = zpack_h(pu1.z, pv1.z); z1.w = zpack_h(pu1.w, pv1.w);
            *(uint4*)(As_u + arow * 32 + p0 * 4) = z0;
            *(uint4*)(As_u + arow * 32 + p1 * 4) = z1;
            if (j < 6) {
                const int kn = (j + 2) * 64;
                pu0 = *(const uint4*)(up + kn);      pu1 = *(const uint4*)(up + kn + 8);
                pv0 = *(const uint4*)(vp + kn);      pv1 = *(const uint4*)(vp + kn + 8);
            }
            asm volatile("s_waitcnt lgkmcnt(0)" ::: "memory");
            __builtin_amdgcn_s_barrier();       // RAW: As(j+1) visible to all
            asm volatile("" ::: "memory");
        }
    }
    // ===== epilogue: segment-max pre-reduced in LDS key tile, sparse flush =====
    const int dbase = sdst[0];
    const int drange = sdst[63] - dbase + 1;
    if (drange <= 16) {
#pragma unroll
        for (int i = 0; i < 16; ++i) ktile[i * 256 + t] = 0u;   // zero tile
        __syncthreads();
#pragma unroll
        for (int mt = 0; mt < 4; ++mt) {
            int base = mt * 16 + (l >> 4) * 4;
            int d0 = sdst[base], d1 = sdst[base + 1], d2 = sdst[base + 2], d3 = sdst[base + 3];
            int r0 = d0 - dbase, r1 = d1 - dbase, r2 = d2 - dbase, r3 = d3 - dbase;
#pragma unroll
            for (int nt = 0; nt < 4; ++nt) {
                int colb = wnb + nt * 16 + lm;
                f32x4 a = acc[mt][nt];
                float m = a[0];
                if (d1 == d0) m = fmaxf(m, a[1]);
                else { atomicMax(ktile + r0 * 256 + colb, fkey(m)); m = a[1]; }
                if (d2 == d1) m = fmaxf(m, a[2]);
                else { atomicMax(ktile + r1 * 256 + colb, fkey(m)); m = a[2]; }
                if (d3 == d2) m = fmaxf(m, a[3]);
                else { atomicMax(ktile + r2 * 256 + colb, fkey(m)); m = a[3]; }
                atomicMax(ktile + r3 * 256 + colb, fkey(m));
            }
        }
        __syncthreads();
#pragma unroll 4
        for (int r = 0; r < 16; ++r) {
            if (r < drange) {
                unsigned int kv = ktile[r * 256 + t];
                if (kv) atomicMax(K + (((size_t)(dbase + r)) << 9) + n0 + t, kv);
            }
        }
    } else {
#pragma unroll
        for (int mt = 0; mt < 4; ++mt) {
            int base = mt * 16 + (l >> 4) * 4;
            int d0 = sdst[base], d1 = sdst[base + 1], d2 = sdst[base + 2], d3 = sdst[base + 3];
#pragma unroll
            for (int nt = 0; nt < 4; ++nt) {
                int col = n0 + wnb + nt * 16 + lm;
                f32x4 a = acc[mt][nt];
                float m = a[0];
                if (d1 == d0) m = fmaxf(m, a[1]); else { kflush(K, d0, col, m); m = a[1]; }
                if (d2 == d1) m = fmaxf(m, a[2]); else { kflush(K, d1, col, m); m = a[2]; }
                if (d3 == d2) m = fmaxf(m, a[3]); else { kflush(K, d2, col, m); m = a[3]; }
                kflush(K, d3, col, m);
            }
        }
    }
}

// ======= decode keys -> h bf16 (x2 vectorized); re-zero keys for next layer =======
__global__ __launch_bounds__(256) void decode_kernel(
    unsigned int* __restrict__ K, const float* __restrict__ b2,
    short* __restrict__ hb) {
    int idx = blockIdx.x * 256 + threadIdx.x;          // 2 keys per thread
    uint2 k = ((uint2*)K)[idx];
    uint2 zz = {0u, 0u};
    ((uint2*)K)[idx] = zz;                             // init for next layer
    int c = (idx << 1) & (HDIM - 1);
    float v0 = 0.f, v1 = 0.f;
    if (k.x != 0u) {
        unsigned int b = (k.x & 0x80000000u) ? (k.x ^ 0x80000000u) : ~k.x;
        v0 = __uint_as_float(b) + b2[c];
    }
    if (k.y != 0u) {
        unsigned int b = (k.y & 0x80000000u) ? (k.y ^ 0x80000000u) : ~k.y;
        v1 = __uint_as_float(b) + b2[c + 1];
    }
    unsigned int o = (unsigned int)f2b(fmaxf(v0, 0.f))
                   | ((unsigned int)f2b(fmaxf(v1, 0.f)) << 16);
    ((unsigned int*)hb)[idx] = o;
}

// ========= MFMA GEMM (FFN), 64x128 tiles, optional sel-gather on A =========
__global__ __launch_bounds__(256) void ffn_gemm_kernel(
    const short* __restrict__ A, const int* __restrict__ sel,
    const short* __restrict__ Wt, const float* __restrict__ bias,
    short* __restrict__ Cb, float* __restrict__ Cf, int relu) {
    __shared__ short As[64 * 32];      // 4 KB
    __shared__ short Bs[128 * 32];     // 8 KB
    const int t = threadIdx.x;
    const int m0 = blockIdx.x * 64, n0 = blockIdx.y * 128;
    const int w = t >> 6, l = t & 63;
    const int wm = (w & 1) * 32, wn = (w >> 1) * 64;
    const int srow = t >> 2, sp = t & 3;
    const int sq = sp ^ ((srow >> 1) & 3);
    const short* ap;
    if (sel) {                                   // fused gather: row -> hb row
        int gr = m0 + srow;                      // 0..4095
        ap = A + (((size_t)((gr >> 9) * SEQ + sel[gr])) << 9);
    } else {
        ap = A + (size_t)(m0 + srow) * HDIM;
    }
    f32x4 acc[2][4] = {};
    for (int kc = 0; kc < HDIM; kc += 32) {
        gld16(ap + kc + sq * 8, As + t * 8);
        stage_tile(Wt + (size_t)n0 * HDIM, kc, Bs, t);
        __syncthreads();
        short8 a[2], b[4];
#pragma unroll
        for (int mt = 0; mt < 2; ++mt) a[mt] = frag_ld(As, wm + mt * 16 + (l & 15), l >> 4);
#pragma unroll
        for (int nt = 0; nt < 4; ++nt) b[nt] = frag_ld(Bs, wn + nt * 16 + (l & 15), l >> 4);
#pragma unroll
        for (int mt = 0; mt < 2; ++mt)
#pragma unroll
            for (int nt = 0; nt < 4; ++nt)
                acc[mt][nt] = __builtin_amdgcn_mfma_f32_16x16x32_bf16(a[mt], b[nt], acc[mt][nt], 0, 0, 0);
        __syncthreads();
    }
#pragma unroll
    for (int mt = 0; mt < 2; ++mt) {
        int m = m0 + wm + mt * 16 + (l >> 4) * 4;
#pragma unroll
        for (int nt = 0; nt < 4; ++nt) {
            int n = n0 + wn + nt * 16 + (l & 15);
            float bv = bias[n];
#pragma unroll
            for (int r = 0; r < 4; ++r) {
                float v = acc[mt][nt][r] + bv;
                if (relu) v = fmaxf(v, 0.f);
                if (Cf) Cf[(size_t)(m + r) * HDIM + n] = v;
                else    Cb[(size_t)(m + r) * HDIM + n] = (short)f2b(v);
            }
        }
    }
}

extern "C" void kernel_launch(void* const* d_in, const int* in_sizes, int n_in,
                              void* d_out, int out_size, void* d_ws, size_t ws_size,
                              hipStream_t stream) {
    const float* x   = (const float*)d_in[0];
    const int*   ei  = (const int*)d_in[1];
    const int*   sel = (const int*)d_in[2];
    const int*   src = ei;
    const int*   dst = ei + EDGES;
    const float* cw1[3] = {(const float*)d_in[4],  (const float*)d_in[8],  (const float*)d_in[12]};
    const float* cb1[3] = {(const float*)d_in[5],  (const float*)d_in[9],  (const float*)d_in[13]};
    const float* cw2[3] = {(const float*)d_in[6],  (const float*)d_in[10], (const float*)d_in[14]};
    const float* cb2[3] = {(const float*)d_in[7],  (const float*)d_in[11], (const float*)d_in[15]};
    const float* fw1 = (const float*)d_in[16];
    const float* fb1 = (const float*)d_in[17];
    const float* fw2 = (const float*)d_in[18];
    const float* fb2 = (const float*)d_in[19];
    float* out = (float*)d_out;

    const size_t MB = 1024 * 1024;
    char* p = (char*)d_ws;
    unsigned int* keys = (unsigned int*)p;                   // 32 MB
    short* U    = (short*)(p + 32 * MB);                     // 16 MB (fp16)
    short* V    = (short*)(p + 48 * MB);                     // 16 MB (fp16)
    short* hb   = (short*)(p + 64 * MB);                     // 16 MB (bf16)
    short* Wall = (short*)(p + 80 * MB);                     // 9 x 0.5 MB conv mats (frag order)
    short* fw1T = Wall + 9 * 512 * 512;                      // FFN mats
    short* fw2T = fw1T + 512 * 512;
    int*   dstS = (int*)(p + 86 * MB);                       // 1 MB
    int*   srcS = (int*)(p + 87 * MB);                       // 1 MB
    int*   hist = (int*)(p + 88 * MB);                       // 64 KB
    int*   curs = hist + N_NODES;                            // 64 KB
    short* t1b  = (short*)(p + 89 * MB);                     // 4 MB

    // --- sort edges by dst (edges constant across layers) ---
    (void)hipMemsetAsync(hist, 0, N_NODES * sizeof(int), stream);
    hist_kernel<<<EDGES / 256, 256, 0, stream>>>(dst, hist);
    scan_kernel<<<1, 256, 0, stream>>>(hist, curs);
    scatter_kernel<<<EDGES / 256, 256, 0, stream>>>(dst, src, curs, dstS, srcS);

    cvt_bf16_kernel<<<8192, 256, 0, stream>>>(x, hb);
    tr_kernel<<<dim3(16, 16, 2), dim3(32, 8), 0, stream>>>(fw1, fw2, fw1T, fw2T);
    prep_weights_all_kernel<<<dim3(16, 16, 9), dim3(32, 8), 0, stream>>>(
        cw1[0], cw2[0], cw1[1], cw2[1], cw1[2], cw2[2], Wall);
    (void)hipMemsetAsync(keys, 0, 32 * MB, stream);          // layer-0 key init

    for (int l = 0; l < 3; ++l) {
        short* WdF  = Wall + (size_t)(l * 3 + 0) * 512 * 512;
        short* w1bF = Wall + (size_t)(l * 3 + 1) * 512 * 512;
        short* W2f  = Wall + (size_t)(l * 3 + 2) * 512 * 512;
        node_gemm_uv_kernel<<<dim3(128, 4), 256, 0, stream>>>(hb, WdF, w1bF, cb1[l], U, V);
        edge_mfma_kernel<<<8192, 256, 0, stream>>>(U, V, W2f, srcS, dstS, keys);
        decode_kernel<<<(N_NODES * HDIM / 2) / 256, 256, 0, stream>>>(keys, cb2[l], hb);
    }

    // FFN: gather fused into GEMM1's A-stage via sel indirection
    ffn_gemm_kernel<<<dim3(64, 4), 256, 0, stream>>>(hb, sel, fw1T, fb1, t1b, nullptr, 1);
    ffn_gemm_kernel<<<dim3(64, 4), 256, 0, stream>>>(t1b, nullptr, fw2T, fb2, nullptr, out, 0);
}

// Round 13
// 717.102 us; speedup vs baseline: 1.5099x; 1.0002x over previous
//
#include <hip/hip_runtime.h>
#include <hip/hip_bf16.h>

// UCCAEncoder: 3x EdgeConv(max) + FFN + gather. R22:
//  - edge kernel (R20 dataflow kept: B direct L2->reg via frag-ordered W2):
//    (a) B loads moved to BOTTOM of each K-step: bc(2j+2)/bn(2j+3) issued
//        right after their old values are consumed -> lead >= oddMFMA+barrier+
//        zpack (~250-400cy) instead of 80cy for bn. Zero extra regs.
//    (b) As DOUBLE-buffered (8->16KB) -> ONE lgkmcnt(0)+barrier per K-step
//        (9 vs 17). WAR proof: As[(j+1)&1] last read in step j-1; every
//        wave's reads complete (own lgkmcnt(0)) before barrier(j-1), which
//        precedes any step-j write. Skew bounded by 1 barrier. No vmcnt
//        drain in loop (B/pu/pv in flight, compiler-counted).
//  - tr_kernel folded into prep (grid z=11): one fewer launch.
//  - keeps: node B-direct (R21), batched frag-order prep, ffn retile+fused
//    gather, decode x2, LDS key-tile epilogue, sorted edges, XCD swizzle.

#define N_NODES 16384
#define EDGES   262144
#define HDIM    512
#define SEQ     2048

typedef __attribute__((ext_vector_type(8))) short short8;
typedef __attribute__((ext_vector_type(8))) _Float16 half8;
typedef __attribute__((ext_vector_type(2))) _Float16 half2v;
typedef __attribute__((ext_vector_type(4))) float f32x4;

__device__ __forceinline__ void gld16(const void* g, void* l) {
    __builtin_amdgcn_global_load_lds(
        (const __attribute__((address_space(1))) void*)g,
        (__attribute__((address_space(3))) void*)l, 16, 0, 0);
}
__device__ __forceinline__ unsigned short f2b(float f) {   // fp32 -> bf16 RNE
    unsigned int x = __float_as_uint(f);
    return (unsigned short)((x + 0x7fffu + ((x >> 16) & 1u)) >> 16);
}
__device__ __forceinline__ unsigned short f2h(float f) {   // fp32 -> fp16 bits
    _Float16 h = (_Float16)f;
    return __builtin_bit_cast(unsigned short, h);
}
// packed fp16: z = max(u+v, 0) (v_pk_add_f16 + v_pk_max_f16)
__device__ __forceinline__ unsigned int zpack_h(unsigned int u, unsigned int v) {
    half2v a = __builtin_bit_cast(half2v, u);
    half2v b = __builtin_bit_cast(half2v, v);
    half2v s = a + b;
    half2v z = {(_Float16)0.f, (_Float16)0.f};
    half2v r = __builtin_elementwise_max(s, z);
    return __builtin_bit_cast(unsigned int, r);
}
// ---- Bk=32 LDS swizzle (A tiles / FFN): slot = seg ^ ((row>>1)&3), row stride 64B
__device__ __forceinline__ short8 frag_ld(const short* S, int row, int q) {
    int p = q ^ ((row >> 1) & 3);
    return *(const short8*)(S + row * 32 + p * 8);
}
__device__ __forceinline__ void stage_tile(const short* G, int kc, short* S, int t) {
#pragma unroll
    for (int it = 0; it < 2; ++it) {
        int lin = it * 256 + t;
        int row = lin >> 2, p = lin & 3;
        int q = p ^ ((row >> 1) & 3);
        gld16(G + (size_t)row * HDIM + kc + q * 8, S + lin * 8);
    }
}
// ---- Bk=64 LDS swizzle (edge A tile): row stride 128B = bank wrap ->
//      slot = seg ^ ((row>>1)&7) ^ (row&1); 8 segs of 8 els per row.
__device__ __forceinline__ half8 frag64(const short* S, int row, int q) {
    int p = q ^ ((row >> 1) & 7) ^ (row & 1);
    return *(const half8*)(S + row * 64 + p * 8);
}

// ================= edge sort (counting sort by dst) =================
__global__ __launch_bounds__(256) void hist_kernel(
    const int* __restrict__ dst, int* __restrict__ hist) {
    int idx = blockIdx.x * 256 + threadIdx.x;
    atomicAdd(&hist[dst[idx]], 1);
}
__global__ __launch_bounds__(256) void scan_kernel(
    const int* __restrict__ hist, int* __restrict__ cursor) {
    __shared__ int part[256];
    const int t = threadIdx.x, base = t * 64;
    int sum = 0;
    for (int i = 0; i < 64; ++i) sum += hist[base + i];
    part[t] = sum;
    __syncthreads();
    int run = 0;
    for (int i = 0; i < t; ++i) run += part[i];
    for (int i = 0; i < 64; ++i) {
        int h = hist[base + i];
        cursor[base + i] = run;
        run += h;
    }
}
__global__ __launch_bounds__(256) void scatter_kernel(
    const int* __restrict__ dst, const int* __restrict__ src,
    int* __restrict__ cursor, int* __restrict__ dstS, int* __restrict__ srcS) {
    int idx = blockIdx.x * 256 + threadIdx.x;
    int d = dst[idx];
    int p = atomicAdd(&cursor[d], 1);
    dstS[p] = d;
    srcS[p] = src[idx];
}

// ================= weights / input prep =================
// grid z = 11: z<9 conv mats (layer=z/3, which=z%3) in MFMA-FRAGMENT order
// (frag (ntile=n>>4,kstep=k>>5) = 64 lanes x 8 els; lane=(n&15)|(((k>>3)&3)<<4));
// which 0/1 bf16, which 2 fp16. z==9/10: FFN fw1/fw2 -> standard [n][k] bf16.
__global__ __launch_bounds__(256) void prep_weights_all_kernel(
    const float* __restrict__ w1_0, const float* __restrict__ w2_0,
    const float* __restrict__ w1_1, const float* __restrict__ w2_1,
    const float* __restrict__ w1_2, const float* __restrict__ w2_2,
    const float* __restrict__ fw1, const float* __restrict__ fw2,
    short* __restrict__ outbase, short* __restrict__ fT1, short* __restrict__ fT2) {
    __shared__ float tile[32][33];
    const int z = blockIdx.z;
    const int k0 = blockIdx.x * 32, n0 = blockIdx.y * 32;
    const int tx = threadIdx.x, ty = threadIdx.y;
    if (z < 9) {
        const int layer = z / 3, which = z % 3;
        const float* w1 = layer == 0 ? w1_0 : (layer == 1 ? w1_1 : w1_2);
        const float* w2 = layer == 0 ? w2_0 : (layer == 1 ? w2_1 : w2_2);
#pragma unroll
        for (int i = 0; i < 4; ++i) {
            int k = k0 + ty + i * 8, n = n0 + tx;
            float v;
            if (which == 0)      v = w1[k * 512 + n] - w1[(k + 512) * 512 + n];
            else if (which == 1) v = w1[(k + 512) * 512 + n];
            else                 v = w2[k * 512 + n];
            tile[ty + i * 8][tx] = v;
        }
        __syncthreads();
        short* out = outbase + (size_t)(layer * 3 + which) * 512 * 512;
#pragma unroll
        for (int i = 0; i < 4; ++i) {
            int n = n0 + ty + i * 8, k = k0 + tx;
            float v = tile[tx][ty + i * 8];
            int lane = (n & 15) | (((k >> 3) & 3) << 4);
            size_t idx = ((size_t)((n >> 4) * 16 + (k >> 5)) * 64 + lane) * 8 + (k & 7);
            out[idx] = (short)(which == 2 ? f2h(v) : f2b(v));
        }
    } else {
        const float* W = (z == 9) ? fw1 : fw2;
        short* T = (z == 9) ? fT1 : fT2;
#pragma unroll
        for (int i = 0; i < 4; ++i)
            tile[ty + i * 8][tx] = W[(k0 + ty + i * 8) * 512 + n0 + tx];
        __syncthreads();
#pragma unroll
        for (int i = 0; i < 4; ++i)
            T[(size_t)(n0 + ty + i * 8) * 512 + k0 + tx] = (short)f2b(tile[tx][ty + i * 8]);
    }
}
__global__ __launch_bounds__(256) void cvt_bf16_kernel(
    const float* __restrict__ x, short* __restrict__ xb) {
    int idx = blockIdx.x * 256 + threadIdx.x;
    float4 v = ((const float4*)x)[idx];
    uint2 o;
    o.x = (unsigned int)f2b(v.x) | ((unsigned int)f2b(v.y) << 16);
    o.y = (unsigned int)f2b(v.z) | ((unsigned int)f2b(v.w) << 16);
    ((uint2*)xb)[idx] = o;
}

// ========== fused U/V node GEMM: B direct L2->reg (frag order), A LDS dbuf ==========
__global__ __launch_bounds__(256, 2) void node_gemm_uv_kernel(
    const short* __restrict__ A, const short* __restrict__ WdF,
    const short* __restrict__ w1bF, const float* __restrict__ b1,
    short* __restrict__ U, short* __restrict__ V) {
    __shared__ short As[2][128 * 32];   // 16 KB
    const int t = threadIdx.x;
    const int m0 = blockIdx.x * 128, n0 = blockIdx.y * 128;
    const int w = t >> 6, l = t & 63;
    const int wm = (w & 1) * 64, wn = (w >> 1) * 64;
    const short* Ag = A + (size_t)m0 * HDIM;
    const short* bpU = WdF + (size_t)((n0 + wn) >> 4) * 8192 + (size_t)l * 8;
    const short* bpV = w1bF + (size_t)((n0 + wn) >> 4) * 8192 + (size_t)l * 8;
    f32x4 aU[4][4] = {}, aV[4][4] = {};
    short8 bu2[2][4], bv2[2][4];
    stage_tile(Ag, 0, As[0], t);
#pragma unroll
    for (int nt = 0; nt < 4; ++nt) bu2[0][nt] = *(const short8*)(bpU + nt * 8192);
#pragma unroll
    for (int nt = 0; nt < 4; ++nt) bv2[0][nt] = *(const short8*)(bpV + nt * 8192);
    asm volatile("s_waitcnt vmcnt(8)" ::: "memory");
    __builtin_amdgcn_s_barrier();
    asm volatile("" ::: "memory");
#pragma unroll
    for (int hh = 0; hh < 16; ++hh) {
        short8 a[4];
#pragma unroll
        for (int mt = 0; mt < 4; ++mt)
            a[mt] = frag_ld(As[hh & 1], wm + mt * 16 + (l & 15), l >> 4);
        if (hh < 15) {
#pragma unroll
            for (int nt = 0; nt < 4; ++nt)
                bu2[(hh + 1) & 1][nt] = *(const short8*)(bpU + nt * 8192 + (hh + 1) * 512);
            stage_tile(Ag, (hh + 1) * 32, As[(hh + 1) & 1], t);
            asm volatile("" ::: "memory");
        }
        __builtin_amdgcn_s_setprio(1);
#pragma unroll
        for (int mt = 0; mt < 4; ++mt)
#pragma unroll
            for (int nt = 0; nt < 4; ++nt)
                aU[mt][nt] = __builtin_amdgcn_mfma_f32_16x16x32_bf16(a[mt], bu2[hh & 1][nt], aU[mt][nt], 0, 0, 0);
        __builtin_amdgcn_s_setprio(0);
        if (hh < 15) {
#pragma unroll
            for (int nt = 0; nt < 4; ++nt)
                bv2[(hh + 1) & 1][nt] = *(const short8*)(bpV + nt * 8192 + (hh + 1) * 512);
        }
        __builtin_amdgcn_s_setprio(1);
#pragma unroll
        for (int mt = 0; mt < 4; ++mt)
#pragma unroll
            for (int nt = 0; nt < 4; ++nt)
                aV[mt][nt] = __builtin_amdgcn_mfma_f32_16x16x32_bf16(a[mt], bv2[hh & 1][nt], aV[mt][nt], 0, 0, 0);
        __builtin_amdgcn_s_setprio(0);
        if (hh < 15) {
            asm volatile("s_waitcnt vmcnt(4) lgkmcnt(0)" ::: "memory");
            __builtin_amdgcn_s_barrier();
            asm volatile("" ::: "memory");
        }
    }
#pragma unroll
    for (int mt = 0; mt < 4; ++mt) {
        int m = m0 + wm + mt * 16 + (l >> 4) * 4;
#pragma unroll
        for (int nt = 0; nt < 4; ++nt) {
            int n = n0 + wn + nt * 16 + (l & 15);
            float bv = b1[n];
#pragma unroll
            for (int r = 0; r < 4; ++r) {
                U[(size_t)(m + r) * HDIM + n] = (short)f2h(aU[mt][nt][r] + bv);
                V[(size_t)(m + r) * HDIM + n] = (short)f2h(aV[mt][nt][r]);
            }
        }
    }
}

// ====== edge GEMM: B direct L2->reg (frag order), As dbuf, 1 barrier/K-step ======
__device__ __forceinline__ unsigned int fkey(float m) {    // monotone fp32->uint
    unsigned int b = __float_as_uint(m);
    return ((int)b < 0) ? ~b : (b | 0x80000000u);
}
__device__ __forceinline__ void kflush(unsigned int* K, int d, int col, float m) {
    atomicMax(K + (((size_t)d) << 9) + col, fkey(m));
}
__global__ __launch_bounds__(256, 3) void edge_mfma_kernel(
    const short* __restrict__ U, const short* __restrict__ V,
    const short* __restrict__ W2f, const int* __restrict__ srcS,
    const int* __restrict__ dstS, unsigned int* __restrict__ K) {
    __shared__ short As[2][64 * 64];         // 16 KB (z, fp16, Bk=64, dbuf)
    __shared__ unsigned int ktile[16 * 256]; // 16 KB (epilogue key tile)
    __shared__ int sdst[64], ssrc[64];
    const int t = threadIdx.x;
    // XCD swizzle: L%8 = XCD; the 2 n-halves of edge-group g are 8 apart (same XCD).
    const int L  = blockIdx.x;                 // 0..8191
    const int g  = (L >> 4) * 8 + (L & 7);     // edge-group 0..4095 (64 edges each)
    const int nh = (L >> 3) & 1;               // n-half
    const int e0 = g * 64, n0 = nh * 256;
    if (t < 64) { sdst[t] = dstS[e0 + t]; ssrc[t] = srcS[e0 + t]; }
    __syncthreads();
    const int w = t >> 6, l = t & 63;
    const int wnb = w * 64;                    // 64-col slice
    const int lm = l & 15;
    const int arow = t >> 2, s0 = (t & 3) * 2; // thread covers 32B (segs s0,s0+1)
    const int perm = ((arow >> 1) & 7) ^ (arow & 1);
    const int p0 = s0 ^ perm, p1 = (s0 + 1) ^ perm;
    const short* up = U + (((size_t)sdst[arow]) << 9) + s0 * 8;
    const short* vp = V + (((size_t)ssrc[arow]) << 9) + s0 * 8;
    // fragment-ordered B: frag (ntile, hh) at W2f + ntile*8192 + hh*512, lane-major.
    const short* bp = W2f + (size_t)((n0 + wnb) >> 4) * 8192 + (size_t)l * 8;
    f32x4 acc[4][4] = {};
    half8 bc[4], bn[4];
    uint4 pu0, pu1, pv0, pv1;
    // ---- prologue: B(0), B(1), A(0)->zpack->As[0], A(1) regs, barrier ----
#pragma unroll
    for (int nt = 0; nt < 4; ++nt) bc[nt] = *(const half8*)(bp + nt * 8192);
#pragma unroll
    for (int nt = 0; nt < 4; ++nt) bn[nt] = *(const half8*)(bp + nt * 8192 + 512);
    pu0 = *(const uint4*)(up);      pu1 = *(const uint4*)(up + 8);
    pv0 = *(const uint4*)(vp);      pv1 = *(const uint4*)(vp + 8);
    {
        uint4 z0, z1;
        z0.x = zpack_h(pu0.x, pv0.x); z0.y = zpack_h(pu0.y, pv0.y);
        z0.z = zpack_h(pu0.z, pv0.z); z0.w = zpack_h(pu0.w, pv0.w);
        z1.x = zpack_h(pu1.x, pv1.x); z1.y = zpack_h(pu1.y, pv1.y);
        z1.z = zpack_h(pu1.z, pv1.z); z1.w = zpack_h(pu1.w, pv1.w);
        unsigned int* du = (unsigned int*)As[0];
        *(uint4*)(du + arow * 32 + p0 * 4) = z0;
        *(uint4*)(du + arow * 32 + p1 * 4) = z1;
    }
    pu0 = *(const uint4*)(up + 64); pu1 = *(const uint4*)(up + 72);
    pv0 = *(const uint4*)(vp + 64); pv1 = *(const uint4*)(vp + 72);
    asm volatile("s_waitcnt lgkmcnt(0)" ::: "memory");
    __builtin_amdgcn_s_barrier();
    asm volatile("" ::: "memory");
    // ---- 8 K-steps, ONE barrier each. Step j reads As[j&1]; zpack writes
    // As[(j+1)&1] (last read in step j-1, completed before barrier(j-1) ->
    // WAR safe; skew bounded by 1 barrier). B loads at BOTTOM of step:
    // bc(2j+2)/bn(2j+3) lead >= oddMFMA+zpack+barrier. No vmcnt drain in loop.
#pragma unroll
    for (int j = 0; j < 8; ++j) {
        const short* Ab = As[j & 1];
        __builtin_amdgcn_s_setprio(1);
#pragma unroll
        for (int mt = 0; mt < 4; ++mt) {
            half8 a = frag64(Ab, mt * 16 + lm, (l >> 4));
#pragma unroll
            for (int nt = 0; nt < 4; ++nt)
                acc[mt][nt] = __builtin_amdgcn_mfma_f32_16x16x32_f16(a, bc[nt], acc[mt][nt], 0, 0, 0);
        }
        __builtin_amdgcn_s_setprio(0);
        if (j < 7) {
#pragma unroll
            for (int nt = 0; nt < 4; ++nt)
                bc[nt] = *(const half8*)(bp + nt * 8192 + (2 * j + 2) * 512);
        }
        __builtin_amdgcn_s_setprio(1);
#pragma unroll
        for (int mt = 0; mt < 4; ++mt) {
            half8 a = frag64(Ab, mt * 16 + lm, 4 + (l >> 4));
#pragma unroll
            for (int nt = 0; nt < 4; ++nt)
                acc[mt][nt] = __builtin_amdgcn_mfma_f32_16x16x32_f16(a, bn[nt], acc[mt][nt], 0, 0, 0);
        }
        __builtin_amdgcn_s_setprio(0);
        if (j < 7) {
#pragma unroll
            for (int nt = 0; nt < 4; ++nt)
                bn[nt] = *(const half8*)(bp + nt * 8192 + (2 * j + 3) * 512);
            // zpack A(j+1) -> As[(j+1)&1]; reload pu/pv <- A(j+2)
            uint4 z0, z1;
            z0.x = zpack_h(pu0.x, pv0.x); z0.y = zpack_h(pu0.y, pv0.y);
            z0.z = zpack_h(pu0.z, pv0.z); z0.w = zpack_h(pu0.w, pv0.w);
            z1.x = zpack_h(pu1.x, pv1.x); z1.y = zpack_h(pu1.y, pv1.y);
            z1.z = zpack_h(pu1.z, pv1.z); z1.w = zpack_h(pu1.w, pv1.w);
            unsigned int* du = (unsigned int*)As[(j + 1) & 1];
            *(uint4*)(du + arow * 32 + p0 * 4) = z0;
            *(uint4*)(du + arow * 32 + p1 * 4) = z1;
            if (j < 6) {
                const int kn = (j + 2) * 64;
                pu0 = *(const uint4*)(up + kn);      pu1 = *(const uint4*)(up + kn + 8);
                pv0 = *(const uint4*)(vp + kn);      pv1 = *(const uint4*)(vp + kn + 8);
            }
        }
        asm volatile("s_waitcnt lgkmcnt(0)" ::: "memory");
        __builtin_amdgcn_s_barrier();
        asm volatile("" ::: "memory");
    }
    // ===== epilogue: segment-max pre-reduced in LDS key tile, sparse flush =====
    const int dbase = sdst[0];
    const int drange = sdst[63] - dbase + 1;
    if (drange <= 16) {
#pragma unroll
        for (int i = 0; i < 16; ++i) ktile[i * 256 + t] = 0u;   // zero tile
        __syncthreads();
#pragma unroll
        for (int mt = 0; mt < 4; ++mt) {
            int base = mt * 16 + (l >> 4) * 4;
            int d0 = sdst[base], d1 = sdst[base + 1], d2 = sdst[base + 2], d3 = sdst[base + 3];
            int r0 = d0 - dbase, r1 = d1 - dbase, r2 = d2 - dbase, r3 = d3 - dbase;
#pragma unroll
            for (int nt = 0; nt < 4; ++nt) {
                int colb = wnb + nt * 16 + lm;
                f32x4 a = acc[mt][nt];
                float m = a[0];
                if (d1 == d0) m = fmaxf(m, a[1]);
                else { atomicMax(ktile + r0 * 256 + colb, fkey(m)); m = a[1]; }
                if (d2 == d1) m = fmaxf(m, a[2]);
                else { atomicMax(ktile + r1 * 256 + colb, fkey(m)); m = a[2]; }
                if (d3 == d2) m = fmaxf(m, a[3]);
                else { atomicMax(ktile + r2 * 256 + colb, fkey(m)); m = a[3]; }
                atomicMax(ktile + r3 * 256 + colb, fkey(m));
            }
        }
        __syncthreads();
#pragma unroll 4
        for (int r = 0; r < 16; ++r) {
            if (r < drange) {
                unsigned int kv = ktile[r * 256 + t];
                if (kv) atomicMax(K + (((size_t)(dbase + r)) << 9) + n0 + t, kv);
            }
        }
    } else {
#pragma unroll
        for (int mt = 0; mt < 4; ++mt) {
            int base = mt * 16 + (l >> 4) * 4;
            int d0 = sdst[base], d1 = sdst[base + 1], d2 = sdst[base + 2], d3 = sdst[base + 3];
#pragma unroll
            for (int nt = 0; nt < 4; ++nt) {
                int col = n0 + wnb + nt * 16 + lm;
                f32x4 a = acc[mt][nt];
                float m = a[0];
                if (d1 == d0) m = fmaxf(m, a[1]); else { kflush(K, d0, col, m); m = a[1]; }
                if (d2 == d1) m = fmaxf(m, a[2]); else { kflush(K, d1, col, m); m = a[2]; }
                if (d3 == d2) m = fmaxf(m, a[3]); else { kflush(K, d2, col, m); m = a[3]; }
                kflush(K, d3, col, m);
            }
        }
    }
}

// ======= decode keys -> h bf16 (x2 vectorized); re-zero keys for next layer =======
__global__ __launch_bounds__(256) void decode_kernel(
    unsigned int* __restrict__ K, const float* __restrict__ b2,
    short* __restrict__ hb) {
    int idx = blockIdx.x * 256 + threadIdx.x;          // 2 keys per thread
    uint2 k = ((uint2*)K)[idx];
    uint2 zz = {0u, 0u};
    ((uint2*)K)[idx] = zz;                             // init for next layer
    int c = (idx << 1) & (HDIM - 1);
    float v0 = 0.f, v1 = 0.f;
    if (k.x != 0u) {
        unsigned int b = (k.x & 0x80000000u) ? (k.x ^ 0x80000000u) : ~k.x;
        v0 = __uint_as_float(b) + b2[c];
    }
    if (k.y != 0u) {
        unsigned int b = (k.y & 0x80000000u) ? (k.y ^ 0x80000000u) : ~k.y;
        v1 = __uint_as_float(b) + b2[c + 1];
    }
    unsigned int o = (unsigned int)f2b(fmaxf(v0, 0.f))
                   | ((unsigned int)f2b(fmaxf(v1, 0.f)) << 16);
    ((unsigned int*)hb)[idx] = o;
}

// ========= MFMA GEMM (FFN), 64x128 tiles, optional sel-gather on A =========
__global__ __launch_bounds__(256) void ffn_gemm_kernel(
    const short* __restrict__ A, const int* __restrict__ sel,
    const short* __restrict__ Wt, const float* __restrict__ bias,
    short* __restrict__ Cb, float* __restrict__ Cf, int relu) {
    __shared__ short As[64 * 32];      // 4 KB
    __shared__ short Bs[128 * 32];     // 8 KB
    const int t = threadIdx.x;
    const int m0 = blockIdx.x * 64, n0 = blockIdx.y * 128;
    const int w = t >> 6, l = t & 63;
    const int wm = (w & 1) * 32, wn = (w >> 1) * 64;
    const int srow = t >> 2, sp = t & 3;
    const int sq = sp ^ ((srow >> 1) & 3);
    const short* ap;
    if (sel) {                                   // fused gather: row -> hb row
        int gr = m0 + srow;                      // 0..4095
        ap = A + (((size_t)((gr >> 9) * SEQ + sel[gr])) << 9);
    } else {
        ap = A + (size_t)(m0 + srow) * HDIM;
    }
    f32x4 acc[2][4] = {};
    for (int kc = 0; kc < HDIM; kc += 32) {
        gld16(ap + kc + sq * 8, As + t * 8);
        stage_tile(Wt + (size_t)n0 * HDIM, kc, Bs, t);
        __syncthreads();
        short8 a[2], b[4];
#pragma unroll
        for (int mt = 0; mt < 2; ++mt) a[mt] = frag_ld(As, wm + mt * 16 + (l & 15), l >> 4);
#pragma unroll
        for (int nt = 0; nt < 4; ++nt) b[nt] = frag_ld(Bs, wn + nt * 16 + (l & 15), l >> 4);
#pragma unroll
        for (int mt = 0; mt < 2; ++mt)
#pragma unroll
            for (int nt = 0; nt < 4; ++nt)
                acc[mt][nt] = __builtin_amdgcn_mfma_f32_16x16x32_bf16(a[mt], b[nt], acc[mt][nt], 0, 0, 0);
        __syncthreads();
    }
#pragma unroll
    for (int mt = 0; mt < 2; ++mt) {
        int m = m0 + wm + mt * 16 + (l >> 4) * 4;
#pragma unroll
        for (int nt = 0; nt < 4; ++nt) {
            int n = n0 + wn + nt * 16 + (l & 15);
            float bv = bias[n];
#pragma unroll
            for (int r = 0; r < 4; ++r) {
                float v = acc[mt][nt][r] + bv;
                if (relu) v = fmaxf(v, 0.f);
                if (Cf) Cf[(size_t)(m + r) * HDIM + n] = v;
                else    Cb[(size_t)(m + r) * HDIM + n] = (short)f2b(v);
            }
        }
    }
}

extern "C" void kernel_launch(void* const* d_in, const int* in_sizes, int n_in,
                              void* d_out, int out_size, void* d_ws, size_t ws_size,
                              hipStream_t stream) {
    const float* x   = (const float*)d_in[0];
    const int*   ei  = (const int*)d_in[1];
    const int*   sel = (const int*)d_in[2];
    const int*   src = ei;
    const int*   dst = ei + EDGES;
    const float* cw1[3] = {(const float*)d_in[4],  (const float*)d_in[8],  (const float*)d_in[12]};
    const float* cb1[3] = {(const float*)d_in[5],  (const float*)d_in[9],  (const float*)d_in[13]};
    const float* cw2[3] = {(const float*)d_in[6],  (const float*)d_in[10], (const float*)d_in[14]};
    const float* cb2[3] = {(const float*)d_in[7],  (const float*)d_in[11], (const float*)d_in[15]};
    const float* fw1 = (const float*)d_in[16];
    const float* fb1 = (const float*)d_in[17];
    const float* fw2 = (const float*)d_in[18];
    const float* fb2 = (const float*)d_in[19];
    float* out = (float*)d_out;

    const size_t MB = 1024 * 1024;
    char* p = (char*)d_ws;
    unsigned int* keys = (unsigned int*)p;                   // 32 MB
    short* U    = (short*)(p + 32 * MB);                     // 16 MB (fp16)
    short* V    = (short*)(p + 48 * MB);                     // 16 MB (fp16)
    short* hb   = (short*)(p + 64 * MB);                     // 16 MB (bf16)
    short* Wall = (short*)(p + 80 * MB);                     // 9 x 0.5 MB conv mats (frag order)
    short* fw1T = Wall + 9 * 512 * 512;                      // FFN mats
    short* fw2T = fw1T + 512 * 512;
    int*   dstS = (int*)(p + 86 * MB);                       // 1 MB
    int*   srcS = (int*)(p + 87 * MB);                       // 1 MB
    int*   hist = (int*)(p + 88 * MB);                       // 64 KB
    int*   curs = hist + N_NODES;                            // 64 KB
    short* t1b  = (short*)(p + 89 * MB);                     // 4 MB

    // --- sort edges by dst (edges constant across layers) ---
    (void)hipMemsetAsync(hist, 0, N_NODES * sizeof(int), stream);
    hist_kernel<<<EDGES / 256, 256, 0, stream>>>(dst, hist);
    scan_kernel<<<1, 256, 0, stream>>>(hist, curs);
    scatter_kernel<<<EDGES / 256, 256, 0, stream>>>(dst, src, curs, dstS, srcS);

    cvt_bf16_kernel<<<8192, 256, 0, stream>>>(x, hb);
    prep_weights_all_kernel<<<dim3(16, 16, 11), dim3(32, 8), 0, stream>>>(
        cw1[0], cw2[0], cw1[1], cw2[1], cw1[2], cw2[2], fw1, fw2, Wall, fw1T, fw2T);
    (void)hipMemsetAsync(keys, 0, 32 * MB, stream);          // layer-0 key init

    for (int l = 0; l < 3; ++l) {
        short* WdF  = Wall + (size_t)(l * 3 + 0) * 512 * 512;
        short* w1bF = Wall + (size_t)(l * 3 + 1) * 512 * 512;
        short* W2f  = Wall + (size_t)(l * 3 + 2) * 512 * 512;
        node_gemm_uv_kernel<<<dim3(128, 4), 256, 0, stream>>>(hb, WdF, w1bF, cb1[l], U, V);
        edge_mfma_kernel<<<8192, 256, 0, stream>>>(U, V, W2f, srcS, dstS, keys);
        decode_kernel<<<(N_NODES * HDIM / 2) / 256, 256, 0, stream>>>(keys, cb2[l], hb);
    }

    // FFN: gather fused into GEMM1's A-stage via sel indirection
    ffn_gemm_kernel<<<dim3(64, 4), 256, 0, stream>>>(hb, sel, fw1T, fb1, t1b, nullptr, 1);
    ffn_gemm_kernel<<<dim3(64, 4), 256, 0, stream>>>(t1b, nullptr, fw2T, fb2, nullptr, out, 0);
}